// Round 7
// baseline (510.150 us; speedup 1.0000x reference)
//
#include <hip/hip_runtime.h>

#define DEV __device__ __forceinline__

typedef __attribute__((ext_vector_type(4))) float floatx4;
typedef __attribute__((ext_vector_type(8))) short short8;
typedef __attribute__((ext_vector_type(4))) unsigned uintx4;

DEV unsigned short f2bf(float f) {
  unsigned u = __float_as_uint(f);
  u += 0x7FFF + ((u >> 16) & 1);
  return (unsigned short)(u >> 16);
}
DEV float bf2f(unsigned short h) { return __uint_as_float(((unsigned)h) << 16); }

// pack two f32 -> bf16x2 dword: single VOP3
DEV unsigned cvtpk(float lo, float hi) {
  unsigned r;
  asm("v_cvt_pk_bf16_f32 %0, %1, %2" : "=v"(r) : "v"(lo), "v"(hi));
  return r;
}

#if __has_builtin(__builtin_amdgcn_exp2f)
#define EXP2(x) __builtin_amdgcn_exp2f(x)
#else
#define EXP2(x) exp2f(x)
#endif

#define GLD16(g, l)                                                            \
  __builtin_amdgcn_global_load_lds(                                            \
      (const __attribute__((address_space(1))) void*)(g),                      \
      (__attribute__((address_space(3))) void*)(l), 16, 0, 0)

DEV int laneid() {
  return __builtin_amdgcn_mbcnt_hi(~0u, __builtin_amdgcn_mbcnt_lo(~0u, 0));
}

// (r0, r1) = cross-lane swap: r0 = [a.lo32 | b.lo32], r1 = [a.hi32 | b.hi32]
DEV void pl32(unsigned a, unsigned b, unsigned& r0, unsigned& r1) {
#if __has_builtin(__builtin_amdgcn_permlane32_swap)
  auto r = __builtin_amdgcn_permlane32_swap(a, b, false, false);
  r0 = (unsigned)r[0];
  r1 = (unsigned)r[1];
#else
  const int ln = laneid();
  const int ix = (ln ^ 32) << 2;
  const unsigned xa = (unsigned)__builtin_amdgcn_ds_bpermute(ix, (int)a);
  const unsigned xb = (unsigned)__builtin_amdgcn_ds_bpermute(ix, (int)b);
  const bool hi = (ln & 32) != 0;
  r0 = hi ? xb : a;
  r1 = hi ? b : xa;
#endif
}

// (r0, r1) per 32-half: r0 = [a.q0 | b.q0 | a.q2 | b.q2], r1 = [a.q1 | b.q1 | a.q3 | b.q3]
DEV void pl16(unsigned a, unsigned b, unsigned& r0, unsigned& r1) {
#if __has_builtin(__builtin_amdgcn_permlane16_swap)
  auto r = __builtin_amdgcn_permlane16_swap(a, b, false, false);
  r0 = (unsigned)r[0];
  r1 = (unsigned)r[1];
#else
  const int ln = laneid();
  const int ix = (ln ^ 16) << 2;
  const unsigned xa = (unsigned)__builtin_amdgcn_ds_bpermute(ix, (int)a);
  const unsigned xb = (unsigned)__builtin_amdgcn_ds_bpermute(ix, (int)b);
  const bool q1 = (ln & 16) != 0;
  r0 = q1 ? xb : a;
  r1 = q1 ? b : xa;
#endif
}

// ---------------------------------------------------------------- prep
__global__ void k_prep(const float* __restrict__ x, const float* __restrict__ pe,
                       const float* __restrict__ w0, const float* __restrict__ w1,
                       const float* __restrict__ w2, const float* __restrict__ w3,
                       unsigned short* __restrict__ wt, float* __restrict__ xf,
                       unsigned short* __restrict__ xb) {
  __shared__ float t[64][65];
  const int bid = blockIdx.x, tid = threadIdx.x;
  if (bid < 1024) {
    const int z = bid >> 8, rem = bid & 255;
    const int bx = rem & 15, by = rem >> 4;
    const int tx = tid & 63, ty = tid >> 6;
    const float* wsel = (z == 0) ? w0 : (z == 1) ? w1 : (z == 2) ? w2 : w3;
    unsigned short* out = wt + (size_t)z * 1048576;
    const int k0 = bx * 64, n0 = by * 64;
    for (int i = ty; i < 64; i += 4)
      t[i][tx] = wsel[(size_t)(k0 + i) * 1024 + n0 + tx];
    __syncthreads();
    for (int i = ty; i < 64; i += 4)
      out[(size_t)(n0 + i) * 1024 + k0 + tx] = f2bf(t[tx][i]);
  } else {
    const int idx = (bid - 1024) * 256 + tid;  // float4 index, 2M total
    const int row = idx >> 8;
    const int c4 = idx & 255;
    const int s = row & 2047;
    const float4 xv = ((const float4*)x)[idx];
    const float4 pv = ((const float4*)pe)[s * 256 + c4];
    float4 r;
    r.x = xv.x + pv.x; r.y = xv.y + pv.y; r.z = xv.z + pv.z; r.w = xv.w + pv.w;
    ((float4*)xf)[idx] = r;
    ushort4 o;
    o.x = f2bf(r.x); o.y = f2bf(r.y); o.z = f2bf(r.z); o.w = f2bf(r.w);
    ((ushort4*)xb)[idx] = o;
  }
}

// ---------------------------------------------------------------- QKV GEMM (merged, 256^2)
// blocks 0..255: C[8192,2048] = xpeb . (wq|wk)^T -> q,k as [b,h,s,d]
// blocks 256..383: Vt[1024,8192] = wt_v . xpeb^T -> [b,h,d,s]
// 256x256 tile, 512 thr / 8 waves (2M x 4N), BK=32 double-buffered (64KB),
// 1 barrier/step; 384 blocks all co-resident (2/CU capacity) -> no tail,
// one launch boundary removed vs separate qk/vt kernels.
__global__ __launch_bounds__(512, 2) void k_gemmqkv(
    const unsigned short* __restrict__ xpeb, const unsigned short* __restrict__ wt,
    const float* __restrict__ bqp, const float* __restrict__ bkp,
    const float* __restrict__ bvp, unsigned short* __restrict__ qb,
    unsigned short* __restrict__ kb, unsigned short* __restrict__ vtb) {
  __shared__ unsigned short As[2][256 * 32];
  __shared__ unsigned short Bs[2][256 * 32];
  const int tid = threadIdx.x;
  const int lane = tid & 63, wave = tid >> 6;   // wave 0..7
  const int quad = lane >> 4, l16 = lane & 15;
  const int wm = wave >> 2, wn = wave & 3;      // 2M x 4N wave grid
  const int id = blockIdx.x;                    // 0..383

  const unsigned short* Ap;
  const unsigned short* Bp;
  int rb, cb, isv;
  if (id < 256) {
    const int xcd = id & 7, j = id >> 3;        // j 0..31
    rb = ((xcd << 2) | (j & 3)) * 256;          // bx 0..31 (A-row band)
    cb = (j >> 2) * 256;                        // by 0..7
    Ap = xpeb;
    Bp = wt;
    isv = 0;
  } else {
    const int id2 = id - 256;                   // 0..127
    const int xcd = id2 & 7, j2 = id2 >> 3;     // j2 0..15
    cb = ((xcd << 2) | (j2 & 3)) * 256;         // token band 0..31
    rb = (j2 >> 2) * 256;                       // d_out band 0..3
    Ap = wt + 2097152;                          // wt_v
    Bp = xpeb;
    isv = 1;
  }

  floatx4 acc[8][4];
  const floatx4 vzero = {0.f, 0.f, 0.f, 0.f};
#pragma unroll
  for (int i = 0; i < 8; ++i)
#pragma unroll
    for (int jj = 0; jj < 4; ++jj) acc[i][jj] = vzero;

#define QSTAGE(ks, buf)                                                        \
  {                                                                            \
    _Pragma("unroll") for (int r = 0; r < 2; ++r) {                            \
      const int c = r * 512 + tid;                                             \
      const int rw = c >> 2;                                                   \
      const int gc = ((c & 3) ^ ((rw >> 1) & 3)) << 3;                         \
      GLD16(Ap + (size_t)(rb + rw) * 1024 + (ks) * 32 + gc,                    \
            As[buf] + (size_t)(r * 512 + wave * 64) * 8);                      \
      GLD16(Bp + (size_t)(cb + rw) * 1024 + (ks) * 32 + gc,                    \
            Bs[buf] + (size_t)(r * 512 + wave * 64) * 8);                      \
    }                                                                          \
  }

  QSTAGE(0, 0);
  for (int ks = 0; ks < 32; ++ks) {
    const int cur = ks & 1;
    __syncthreads();
    if (ks + 1 < 32) QSTAGE(ks + 1, cur ^ 1);
    short8 fa[8], fb[4];
#pragma unroll
    for (int i = 0; i < 8; ++i)
      fa[i] = *(const short8*)(As[cur] + (wm * 128 + i * 16 + l16) * 32 +
                               ((quad ^ ((l16 >> 1) & 3)) << 3));
#pragma unroll
    for (int i = 0; i < 4; ++i)
      fb[i] = *(const short8*)(Bs[cur] + (wn * 64 + i * 16 + l16) * 32 +
                               ((quad ^ ((l16 >> 1) & 3)) << 3));
#pragma unroll
    for (int mi = 0; mi < 8; ++mi)
#pragma unroll
      for (int ni = 0; ni < 4; ++ni)
        acc[mi][ni] = __builtin_amdgcn_mfma_f32_16x16x32_bf16(fa[mi], fb[ni],
                                                              acc[mi][ni], 0, 0, 0);
  }
#undef QSTAGE

  if (!isv) {
    const int which = cb >> 10;  // by 0..3 -> q, 4..7 -> k
    const float* bias = which ? bkp : bqp;
    unsigned short* out = which ? kb : qb;
#pragma unroll
    for (int ni = 0; ni < 4; ++ni) {
      const int col = cb + wn * 64 + ni * 16 + l16;
      const int cl = col & 1023;
      const float bvv = bias[cl];
      const int hh = cl >> 6, d = cl & 63;
#pragma unroll
      for (int mi = 0; mi < 8; ++mi) {
#pragma unroll
        for (int r = 0; r < 4; ++r) {
          const int row = rb + wm * 128 + mi * 16 + quad * 4 + r;
          const int bb = row >> 11, s = row & 2047;
          out[((size_t)(bb * 16 + hh) * 2048 + s) * 64 + d] = f2bf(acc[mi][ni][r] + bvv);
        }
      }
    }
  } else {
#pragma unroll
    for (int mi = 0; mi < 8; ++mi) {
#pragma unroll
      for (int r = 0; r < 4; ++r) {
        const int row = rb + wm * 128 + mi * 16 + quad * 4 + r;  // d_out
        const float bvv = bvp[row];
#pragma unroll
        for (int ni = 0; ni < 4; ++ni) {
          const int col = cb + wn * 64 + ni * 16 + l16;  // token
          vtb[((size_t)(col >> 11) * 1024 + row) * 2048 + (col & 2047)] =
              f2bf(acc[mi][ni][r] + bvv);
        }
      }
    }
  }
}

// ---------------------------------------------------------------- out-proj GEMM
// 128^2 tile, BK=32 double-buffered, 2-way-safe swizzle.
#define GSTAGE(Aptr, Bptr, RB, CB, ks, buf)                                    \
  {                                                                            \
    _Pragma("unroll") for (int r = 0; r < 2; ++r) {                            \
      const int c = r * 256 + tid;                                             \
      const int rw = c >> 2;                                                   \
      const int gc = ((c & 3) ^ ((rw >> 1) & 3)) << 3;                         \
      GLD16((Aptr) + (size_t)((RB) + rw) * 1024 + (ks) * 32 + gc,              \
            As[buf] + (size_t)(r * 256 + wave * 64) * 8);                      \
      GLD16((Bptr) + (size_t)((CB) + rw) * 1024 + (ks) * 32 + gc,              \
            Bs[buf] + (size_t)(r * 256 + wave * 64) * 8);                      \
    }                                                                          \
  }

__global__ __launch_bounds__(256, 4) void k_gemmo(
    const unsigned short* __restrict__ A, const unsigned short* __restrict__ Bt,
    const float* __restrict__ bias, unsigned short* __restrict__ out) {
  __shared__ unsigned short As[2][128 * 32];
  __shared__ unsigned short Bs[2][128 * 32];
  const int tid = threadIdx.x;
  const int lane = tid & 63, wave = tid >> 6;
  const int quad = lane >> 4, l16 = lane & 15;
  const int wm = wave >> 1, wn = wave & 1;
  const int id = blockIdx.x;  // 0..511
  const int xcd = id & 7, j = id >> 3;
  const int bx = (xcd << 3) | (j & 7), by = j >> 3;  // bx 0..63, by 0..7
  const int rb = bx * 128, cb = by * 128;

  floatx4 acc[4][4];
  const floatx4 vzero = {0.f, 0.f, 0.f, 0.f};
#pragma unroll
  for (int i = 0; i < 4; ++i)
#pragma unroll
    for (int jj = 0; jj < 4; ++jj) acc[i][jj] = vzero;

  GSTAGE(A, Bt, rb, cb, 0, 0);
  for (int ks = 0; ks < 32; ++ks) {
    const int cur = ks & 1;
    __syncthreads();
    if (ks + 1 < 32) GSTAGE(A, Bt, rb, cb, ks + 1, cur ^ 1);
    short8 fa[4], fb[4];
#pragma unroll
    for (int i = 0; i < 4; ++i) {
      fa[i] = *(const short8*)(As[cur] + (wm * 64 + i * 16 + l16) * 32 +
                               ((quad ^ ((l16 >> 1) & 3)) << 3));
      fb[i] = *(const short8*)(Bs[cur] + (wn * 64 + i * 16 + l16) * 32 +
                               ((quad ^ ((l16 >> 1) & 3)) << 3));
    }
#pragma unroll
    for (int mi = 0; mi < 4; ++mi)
#pragma unroll
      for (int ni = 0; ni < 4; ++ni)
        acc[mi][ni] = __builtin_amdgcn_mfma_f32_16x16x32_bf16(fa[mi], fb[ni],
                                                              acc[mi][ni], 0, 0, 0);
  }

#pragma unroll
  for (int ni = 0; ni < 4; ++ni) {
    const int col = cb + wn * 64 + ni * 16 + l16;
    const float bvv = bias[col];
#pragma unroll
    for (int mi = 0; mi < 4; ++mi) {
#pragma unroll
      for (int r = 0; r < 4; ++r) {
        const int row = rb + wm * 64 + mi * 16 + quad * 4 + r;
        out[(size_t)row * 1024 + col] = f2bf(acc[mi][ni][r] + bvv);
      }
    }
  }
}

// ---------------------------------------------------------------- flash attn v9
// LDS ELIMINATED. Arithmetic (r6): the K/V LDS round-trip cost ~50us of the
// 82us kernel (4 blk x 4 waves x 16 ds_read_b128 x 12cyc x 32kt = 41us read
// + ~10us GLD16 writes, CU-serialized), and all 4 waves read IDENTICAL K
// frags. K/V are L2-resident (per-XCD working set ~1.5MB < 4MB), so read
// fragments directly from global: 16B/lane contiguous, 64B-sector coalesced.
// No LDS, no barriers, pure dataflow. V loads issue before the 32-deep
// v_exp chain (~256cyc) which hides their L2 latency; K-load stalls covered
// by 16 waves/CU TLP. VGPR ~120 within the (256,4) 128-cap.
__global__ __launch_bounds__(256, 4) void k_flash(
    const unsigned short* __restrict__ Q, const unsigned short* __restrict__ Kb,
    const unsigned short* __restrict__ Vt, unsigned short* __restrict__ AO) {
  const int tid = threadIdx.x, lane = tid & 63, wave = tid >> 6;
  const int quad = lane >> 4, l16 = lane & 15;
  const int g = blockIdx.x;            // 0..1023
  const int li = g >> 3;               // 0..127
  const int bh = (g & 7) * 8 + (li >> 4);
  const int qt = li & 15;              // 128-row q block
  const int b = bh >> 4, h = bh & 15;

  const unsigned short* Kh = Kb + (size_t)bh * 2048 * 64;
  const unsigned short* Vh = Vt + (size_t)bh * 64 * 2048;

  const float LAMBDA = 0.125f * 1.4426950408889634f;
  short8 aq[2][2];
  {
    const unsigned short* Qb = Q + ((size_t)bh * 2048 + qt * 128 + wave * 32) * 64;
#pragma unroll
    for (int qi = 0; qi < 2; ++qi)
#pragma unroll
      for (int c = 0; c < 2; ++c) {
        const short8 raw =
            *(const short8*)(Qb + (size_t)(qi * 16 + l16) * 64 + c * 32 + quad * 8);
        short8 sv;
#pragma unroll
        for (int j = 0; j < 8; ++j)
          sv[j] = (short)f2bf(bf2f((unsigned short)raw[j]) * LAMBDA);
        aq[qi][c] = sv;
      }
  }

  short8 onesv;  // bf16 1.0 in all 8 slots
#pragma unroll
  for (int j = 0; j < 8; ++j) onesv[j] = (short)0x3F80;

  const floatx4 vzero = {0.f, 0.f, 0.f, 0.f};
  floatx4 o[2][4];
#pragma unroll
  for (int qi = 0; qi < 2; ++qi)
#pragma unroll
    for (int di = 0; di < 4; ++di) o[qi][di] = vzero;
  floatx4 lacc[2] = {vzero, vzero};  // denominators, o-row layout (quad*4+r)

  for (int kt = 0; kt < 32; ++kt) {
    const unsigned short* Kt = Kh + (size_t)kt * 64 * 64;
    const unsigned short* Vp = Vh + (size_t)kt * 64;

    // K fragments direct from L2: fk[ni][cc][j] = K[kt*64+ni*16+l16][cc*32+quad*8+j]
    short8 fk[4][2];
#pragma unroll
    for (int ni = 0; ni < 4; ++ni)
#pragma unroll
      for (int cc = 0; cc < 2; ++cc)
        fk[ni][cc] = *(const short8*)(Kt + (size_t)(ni * 16 + l16) * 64 +
                                      cc * 32 + quad * 8);

    // QK^T: p[qi][ni][r] = S[key=ni*16+quad*4+r][q=l16]
    floatx4 p[2][4];
    __builtin_amdgcn_s_setprio(1);
#pragma unroll
    for (int qi = 0; qi < 2; ++qi)
#pragma unroll
      for (int ni = 0; ni < 4; ++ni) {
        floatx4 t = vzero;
#pragma unroll
        for (int cc = 0; cc < 2; ++cc)
          t = __builtin_amdgcn_mfma_f32_16x16x32_bf16(fk[ni][cc], aq[qi][cc], t, 0, 0, 0);
        p[qi][ni] = t;
      }
    __builtin_amdgcn_s_setprio(0);

    // V fragments direct from L2 (issued before exp chain -> latency hidden):
    // fv[di][ch][j] = V[d=di*16+l16][key=kt*64+ch*32+quad*8+j]
    short8 fv[4][2];
#pragma unroll
    for (int di = 0; di < 4; ++di)
#pragma unroll
      for (int ch = 0; ch < 2; ++ch)
        fv[di][ch] = *(const short8*)(Vp + (size_t)(di * 16 + l16) * 2048 +
                                      ch * 32 + quad * 8);

    // exp2 (32 per lane)
#pragma unroll
    for (int qi = 0; qi < 2; ++qi)
#pragma unroll
      for (int ni = 0; ni < 4; ++ni)
#pragma unroll
        for (int r = 0; r < 4; ++r) p[qi][ni][r] = EXP2(p[qi][ni][r]);

    // pack + permlane transpose -> PV A-operand, then denominator + PV
#pragma unroll
    for (int ch = 0; ch < 2; ++ch) {
      short8 apv[2];
#pragma unroll
      for (int qi = 0; qi < 2; ++qi) {
        const unsigned A0 = cvtpk(p[qi][2 * ch][0], p[qi][2 * ch][1]);
        const unsigned A1 = cvtpk(p[qi][2 * ch][2], p[qi][2 * ch][3]);
        const unsigned B0 = cvtpk(p[qi][2 * ch + 1][0], p[qi][2 * ch + 1][1]);
        const unsigned B1 = cvtpk(p[qi][2 * ch + 1][2], p[qi][2 * ch + 1][3]);
        unsigned P0, Q0, P1, Q1, T0, T1, T2, T3;
        pl32(A0, B0, P0, Q0);
        pl32(A1, B1, P1, Q1);
        pl16(P0, Q0, T0, T2);
        pl16(P1, Q1, T1, T3);
        union { uintx4 u; short8 s; } cv;
        cv.u[0] = T0; cv.u[1] = T1; cv.u[2] = T2; cv.u[3] = T3;
        apv[qi] = cv.s;
      }
      __builtin_amdgcn_s_setprio(1);
#pragma unroll
      for (int qi = 0; qi < 2; ++qi)
        lacc[qi] = __builtin_amdgcn_mfma_f32_16x16x32_bf16(apv[qi], onesv, lacc[qi], 0, 0, 0);
#pragma unroll
      for (int di = 0; di < 4; ++di)
#pragma unroll
        for (int qi = 0; qi < 2; ++qi)
          o[qi][di] = __builtin_amdgcn_mfma_f32_16x16x32_bf16(apv[qi], fv[di][ch], o[qi][di], 0, 0, 0);
      __builtin_amdgcn_s_setprio(0);
    }
  }

#pragma unroll
  for (int qi = 0; qi < 2; ++qi) {
    float invl[4];
#pragma unroll
    for (int r = 0; r < 4; ++r) invl[r] = __builtin_amdgcn_rcpf(lacc[qi][r]);
#pragma unroll
    for (int di = 0; di < 4; ++di) {
#pragma unroll
      for (int r = 0; r < 4; ++r) {
        const int s = qt * 128 + wave * 32 + qi * 16 + quad * 4 + r;
        const int col = h * 64 + di * 16 + l16;
        AO[((size_t)b * 2048 + s) * 1024 + col] = f2bf(o[qi][di][r] * invl[r]);
      }
    }
  }
}

// ---------------------------------------------------------------- residual+LN
__global__ __launch_bounds__(256) void k_ln(
    const unsigned short* __restrict__ proj, const float* __restrict__ xpe,
    const float* __restrict__ gamma, const float* __restrict__ beta,
    float* __restrict__ out) {
  const int row = blockIdx.x, tid = threadIdx.x;
  const int lane = tid & 63, wave = tid >> 6;
  const float4 xv = ((const float4*)(xpe + (size_t)row * 1024))[tid];
  const ushort4 pv = ((const ushort4*)(proj + (size_t)row * 1024))[tid];
  const float h0 = xv.x + bf2f(pv.x);
  const float h1 = xv.y + bf2f(pv.y);
  const float h2 = xv.z + bf2f(pv.z);
  const float h3 = xv.w + bf2f(pv.w);
  float s = h0 + h1 + h2 + h3;
  float s2 = h0 * h0 + h1 * h1 + h2 * h2 + h3 * h3;
#pragma unroll
  for (int m = 1; m < 64; m <<= 1) {
    s += __shfl_xor(s, m);
    s2 += __shfl_xor(s2, m);
  }
  __shared__ float rs[4], rq[4];
  if (lane == 0) { rs[wave] = s; rq[wave] = s2; }
  __syncthreads();
  s = rs[0] + rs[1] + rs[2] + rs[3];
  s2 = rq[0] + rq[1] + rq[2] + rq[3];
  const float mu = s * (1.f / 1024.f);
  const float var = s2 * (1.f / 1024.f) - mu * mu;
  const float rstd = rsqrtf(var + 1e-5f);
  const float4 gv = ((const float4*)gamma)[tid];
  const float4 bvv = ((const float4*)beta)[tid];
  float4 ov;
  ov.x = (h0 - mu) * rstd * gv.x + bvv.x;
  ov.y = (h1 - mu) * rstd * gv.y + bvv.y;
  ov.z = (h2 - mu) * rstd * gv.z + bvv.z;
  ov.w = (h3 - mu) * rstd * gv.w + bvv.w;
  ((float4*)(out + (size_t)row * 1024))[tid] = ov;
}

// ---------------------------------------------------------------- launch
extern "C" void kernel_launch(void* const* d_in, const int* in_sizes, int n_in,
                              void* d_out, int out_size, void* d_ws, size_t ws_size,
                              hipStream_t stream) {
  const float* x = (const float*)d_in[0];
  const float* wq = (const float*)d_in[1];
  const float* bq = (const float*)d_in[2];
  const float* wk = (const float*)d_in[3];
  const float* bk = (const float*)d_in[4];
  const float* wv = (const float*)d_in[5];
  const float* bv = (const float*)d_in[6];
  const float* wo = (const float*)d_in[7];
  const float* bo = (const float*)d_in[8];
  const float* gamma = (const float*)d_in[9];
  const float* beta = (const float*)d_in[10];
  const float* pe = (const float*)d_in[11];

  if (ws_size < 125829120) return;  // need 120 MB scratch

  char* w = (char*)d_ws;
  unsigned short* wt = (unsigned short*)(w);               // 4x 1024x1024 bf16 (8 MB)
  float* xpef = (float*)(w + 8388608);                     // 8192x1024 f32 (32 MB)
  unsigned short* xpeb = (unsigned short*)(w + 41943040);  // 8192x1024 bf16 (16 MB)
  unsigned short* qb = (unsigned short*)(w + 58720256);    // 16 MB
  unsigned short* kb = (unsigned short*)(w + 75497472);    // 16 MB
  unsigned short* vtb = (unsigned short*)(w + 92274688);   // 16 MB
  unsigned short* aob = (unsigned short*)(w + 109051904);  // 16 MB
  unsigned short* projb = qb;                              // alias: Q dead after flash

  k_prep<<<9216, 256, 0, stream>>>(x, pe, wq, wk, wv, wo, wt, xpef, xpeb);
  k_gemmqkv<<<384, 512, 0, stream>>>(xpeb, wt, bq, bk, bv, qb, kb, vtb);
  k_flash<<<1024, 256, 0, stream>>>(qb, kb, vtb, aob);
  k_gemmo<<<512, 256, 0, stream>>>(aob, wt + 3145728, bo, projb);
  k_ln<<<8192, 256, 0, stream>>>(projb, xpef, gamma, beta, (float*)d_out);
}

// Round 8
// 374.341 us; speedup vs baseline: 1.3628x; 1.3628x over previous
//
#include <hip/hip_runtime.h>

#define DEV __device__ __forceinline__

typedef __attribute__((ext_vector_type(4))) float floatx4;
typedef __attribute__((ext_vector_type(8))) short short8;
typedef __attribute__((ext_vector_type(4))) unsigned uintx4;

DEV unsigned short f2bf(float f) {
  unsigned u = __float_as_uint(f);
  u += 0x7FFF + ((u >> 16) & 1);
  return (unsigned short)(u >> 16);
}
DEV float bf2f(unsigned short h) { return __uint_as_float(((unsigned)h) << 16); }

// pack two f32 -> bf16x2 dword: single VOP3
DEV unsigned cvtpk(float lo, float hi) {
  unsigned r;
  asm("v_cvt_pk_bf16_f32 %0, %1, %2" : "=v"(r) : "v"(lo), "v"(hi));
  return r;
}

#if __has_builtin(__builtin_amdgcn_exp2f)
#define EXP2(x) __builtin_amdgcn_exp2f(x)
#else
#define EXP2(x) exp2f(x)
#endif

#define GLD16(g, l)                                                            \
  __builtin_amdgcn_global_load_lds(                                            \
      (const __attribute__((address_space(1))) void*)(g),                      \
      (__attribute__((address_space(3))) void*)(l), 16, 0, 0)

DEV int laneid() {
  return __builtin_amdgcn_mbcnt_hi(~0u, __builtin_amdgcn_mbcnt_lo(~0u, 0));
}

// (r0, r1) = cross-lane swap: r0 = [a.lo32 | b.lo32], r1 = [a.hi32 | b.hi32]
DEV void pl32(unsigned a, unsigned b, unsigned& r0, unsigned& r1) {
#if __has_builtin(__builtin_amdgcn_permlane32_swap)
  auto r = __builtin_amdgcn_permlane32_swap(a, b, false, false);
  r0 = (unsigned)r[0];
  r1 = (unsigned)r[1];
#else
  const int ln = laneid();
  const int ix = (ln ^ 32) << 2;
  const unsigned xa = (unsigned)__builtin_amdgcn_ds_bpermute(ix, (int)a);
  const unsigned xb = (unsigned)__builtin_amdgcn_ds_bpermute(ix, (int)b);
  const bool hi = (ln & 32) != 0;
  r0 = hi ? xb : a;
  r1 = hi ? b : xa;
#endif
}

// (r0, r1) per 32-half: r0 = [a.q0 | b.q0 | a.q2 | b.q2], r1 = [a.q1 | b.q1 | a.q3 | b.q3]
DEV void pl16(unsigned a, unsigned b, unsigned& r0, unsigned& r1) {
#if __has_builtin(__builtin_amdgcn_permlane16_swap)
  auto r = __builtin_amdgcn_permlane16_swap(a, b, false, false);
  r0 = (unsigned)r[0];
  r1 = (unsigned)r[1];
#else
  const int ln = laneid();
  const int ix = (ln ^ 16) << 2;
  const unsigned xa = (unsigned)__builtin_amdgcn_ds_bpermute(ix, (int)a);
  const unsigned xb = (unsigned)__builtin_amdgcn_ds_bpermute(ix, (int)b);
  const bool q1 = (ln & 16) != 0;
  r0 = q1 ? xb : a;
  r1 = q1 ? b : xa;
#endif
}

// ---------------------------------------------------------------- prep
__global__ void k_prep(const float* __restrict__ x, const float* __restrict__ pe,
                       const float* __restrict__ w0, const float* __restrict__ w1,
                       const float* __restrict__ w2, const float* __restrict__ w3,
                       unsigned short* __restrict__ wt, float* __restrict__ xf,
                       unsigned short* __restrict__ xb) {
  __shared__ float t[64][65];
  const int bid = blockIdx.x, tid = threadIdx.x;
  if (bid < 1024) {
    const int z = bid >> 8, rem = bid & 255;
    const int bx = rem & 15, by = rem >> 4;
    const int tx = tid & 63, ty = tid >> 6;
    const float* wsel = (z == 0) ? w0 : (z == 1) ? w1 : (z == 2) ? w2 : w3;
    unsigned short* out = wt + (size_t)z * 1048576;
    const int k0 = bx * 64, n0 = by * 64;
    for (int i = ty; i < 64; i += 4)
      t[i][tx] = wsel[(size_t)(k0 + i) * 1024 + n0 + tx];
    __syncthreads();
    for (int i = ty; i < 64; i += 4)
      out[(size_t)(n0 + i) * 1024 + k0 + tx] = f2bf(t[tx][i]);
  } else {
    const int idx = (bid - 1024) * 256 + tid;  // float4 index, 2M total
    const int row = idx >> 8;
    const int c4 = idx & 255;
    const int s = row & 2047;
    const float4 xv = ((const float4*)x)[idx];
    const float4 pv = ((const float4*)pe)[s * 256 + c4];
    float4 r;
    r.x = xv.x + pv.x; r.y = xv.y + pv.y; r.z = xv.z + pv.z; r.w = xv.w + pv.w;
    ((float4*)xf)[idx] = r;
    ushort4 o;
    o.x = f2bf(r.x); o.y = f2bf(r.y); o.z = f2bf(r.z); o.w = f2bf(r.w);
    ((ushort4*)xb)[idx] = o;
  }
}

// ---------------------------------------------------------------- GEMM core
// 128x128 tile, BK=32 double-buffered, 1 barrier/step. 2-way-safe swizzle
// (chunk ^ ((row>>1)&3)), applied both sides (stage source + frag read).
#define GSTAGE(Aptr, Bptr, RB, CB, ks, buf)                                    \
  {                                                                            \
    _Pragma("unroll") for (int r = 0; r < 2; ++r) {                            \
      const int c = r * 256 + tid;                                             \
      const int rw = c >> 2;                                                   \
      const int gc = ((c & 3) ^ ((rw >> 1) & 3)) << 3;                         \
      GLD16((Aptr) + (size_t)((RB) + rw) * 1024 + (ks) * 32 + gc,              \
            As[buf] + (size_t)(r * 256 + wave * 64) * 8);                      \
      GLD16((Bptr) + (size_t)((CB) + rw) * 1024 + (ks) * 32 + gc,              \
            Bs[buf] + (size_t)(r * 256 + wave * 64) * 8);                      \
    }                                                                          \
  }

#define GEMM_CORE(Aptr, Bptr, RB, CB)                                          \
  GSTAGE(Aptr, Bptr, RB, CB, 0, 0);                                            \
  for (int ks = 0; ks < 32; ++ks) {                                            \
    const int cur = ks & 1;                                                    \
    __syncthreads();                                                           \
    if (ks + 1 < 32) GSTAGE(Aptr, Bptr, RB, CB, ks + 1, cur ^ 1);              \
    short8 fa[4], fb[4];                                                       \
    _Pragma("unroll") for (int i = 0; i < 4; ++i) {                            \
      fa[i] = *(const short8*)(As[cur] + (wm * 64 + i * 16 + l16) * 32 +       \
                               ((quad ^ ((l16 >> 1) & 3)) << 3));              \
      fb[i] = *(const short8*)(Bs[cur] + (wn * 64 + i * 16 + l16) * 32 +       \
                               ((quad ^ ((l16 >> 1) & 3)) << 3));              \
    }                                                                          \
    _Pragma("unroll") for (int mi = 0; mi < 4; ++mi)                           \
        _Pragma("unroll") for (int ni = 0; ni < 4; ++ni) acc[mi][ni] =         \
        __builtin_amdgcn_mfma_f32_16x16x32_bf16(fa[mi], fb[ni],                \
                                                acc[mi][ni], 0, 0, 0);         \
  }

// ---------------------------------------------------------------- QK GEMM (256^2)
// 256 blocks = exactly 1/CU, no tail, balanced.
__global__ __launch_bounds__(512, 2) void k_gemmqk(
    const unsigned short* __restrict__ xpeb, const unsigned short* __restrict__ wt,
    const float* __restrict__ bqp, const float* __restrict__ bkp,
    unsigned short* __restrict__ qb, unsigned short* __restrict__ kb) {
  __shared__ unsigned short As[2][256 * 32];
  __shared__ unsigned short Bs[2][256 * 32];
  const int tid = threadIdx.x;
  const int lane = tid & 63, wave = tid >> 6;   // wave 0..7
  const int quad = lane >> 4, l16 = lane & 15;
  const int wm = wave >> 2, wn = wave & 3;      // 2M x 4N wave grid
  const int id = blockIdx.x;                    // 0..255
  const int xcd = id & 7, j = id >> 3;          // j 0..31
  const int bx = (xcd << 2) | (j & 3);          // 0..31
  const int by = j >> 2;                        // 0..7
  const int rb = bx * 256, cb = by * 256;

  floatx4 acc[8][4];
  const floatx4 vzero = {0.f, 0.f, 0.f, 0.f};
#pragma unroll
  for (int i = 0; i < 8; ++i)
#pragma unroll
    for (int jj = 0; jj < 4; ++jj) acc[i][jj] = vzero;

#define QSTAGE(ks, buf)                                                        \
  {                                                                            \
    _Pragma("unroll") for (int r = 0; r < 2; ++r) {                            \
      const int c = r * 512 + tid;                                             \
      const int rw = c >> 2;                                                   \
      const int gc = ((c & 3) ^ ((rw >> 1) & 3)) << 3;                         \
      GLD16(xpeb + (size_t)(rb + rw) * 1024 + (ks) * 32 + gc,                  \
            As[buf] + (size_t)(r * 512 + wave * 64) * 8);                      \
      GLD16(wt + (size_t)(cb + rw) * 1024 + (ks) * 32 + gc,                    \
            Bs[buf] + (size_t)(r * 512 + wave * 64) * 8);                      \
    }                                                                          \
  }

  QSTAGE(0, 0);
  for (int ks = 0; ks < 32; ++ks) {
    const int cur = ks & 1;
    __syncthreads();
    if (ks + 1 < 32) QSTAGE(ks + 1, cur ^ 1);
    short8 fa[8], fb[4];
#pragma unroll
    for (int i = 0; i < 8; ++i)
      fa[i] = *(const short8*)(As[cur] + (wm * 128 + i * 16 + l16) * 32 +
                               ((quad ^ ((l16 >> 1) & 3)) << 3));
#pragma unroll
    for (int i = 0; i < 4; ++i)
      fb[i] = *(const short8*)(Bs[cur] + (wn * 64 + i * 16 + l16) * 32 +
                               ((quad ^ ((l16 >> 1) & 3)) << 3));
#pragma unroll
    for (int mi = 0; mi < 8; ++mi)
#pragma unroll
      for (int ni = 0; ni < 4; ++ni)
        acc[mi][ni] = __builtin_amdgcn_mfma_f32_16x16x32_bf16(fa[mi], fb[ni],
                                                              acc[mi][ni], 0, 0, 0);
  }
#undef QSTAGE

  const int which = cb >> 10;  // by 0..3 -> q, 4..7 -> k
  const float* bias = which ? bkp : bqp;
  unsigned short* out = which ? kb : qb;
#pragma unroll
  for (int ni = 0; ni < 4; ++ni) {
    const int col = cb + wn * 64 + ni * 16 + l16;
    const int cl = col & 1023;
    const float bvv = bias[cl];
    const int hh = cl >> 6, d = cl & 63;
#pragma unroll
    for (int mi = 0; mi < 8; ++mi) {
#pragma unroll
      for (int r = 0; r < 4; ++r) {
        const int row = rb + wm * 128 + mi * 16 + quad * 4 + r;
        const int bb = row >> 11, s = row & 2047;
        out[((size_t)(bb * 16 + hh) * 2048 + s) * 64 + d] = f2bf(acc[mi][ni][r] + bvv);
      }
    }
  }
}

// ---------------------------------------------------------------- Vt GEMM (128^2)
__global__ __launch_bounds__(256, 4) void k_gemmvt(
    const unsigned short* __restrict__ xpeb, const unsigned short* __restrict__ wt,
    const float* __restrict__ bvp, unsigned short* __restrict__ vtb) {
  __shared__ unsigned short As[2][128 * 32];
  __shared__ unsigned short Bs[2][128 * 32];
  const int tid = threadIdx.x;
  const int lane = tid & 63, wave = tid >> 6;
  const int quad = lane >> 4, l16 = lane & 15;
  const int wm = wave >> 1, wn = wave & 1;
  const int id = blockIdx.x;  // 0..511
  const int xcd = id & 7, j = id >> 3;
  const int by = (xcd << 3) | (j & 7), bx = j >> 3;  // by 0..63 token, bx 0..7 d_out
  const int rb = bx * 128, cb = by * 128;

  floatx4 acc[4][4];
  const floatx4 vzero = {0.f, 0.f, 0.f, 0.f};
#pragma unroll
  for (int i = 0; i < 4; ++i)
#pragma unroll
    for (int jj = 0; jj < 4; ++jj) acc[i][jj] = vzero;

  GEMM_CORE(wt + 2097152, xpeb, rb, cb);

#pragma unroll
  for (int mi = 0; mi < 4; ++mi) {
#pragma unroll
    for (int r = 0; r < 4; ++r) {
      const int row = rb + wm * 64 + mi * 16 + quad * 4 + r;  // d_out = h*64+d
      const float bvv = bvp[row];
#pragma unroll
      for (int ni = 0; ni < 4; ++ni) {
        const int col = cb + wn * 64 + ni * 16 + l16;  // token
        vtb[((size_t)(col >> 11) * 1024 + row) * 2048 + (col & 2047)] =
            f2bf(acc[mi][ni][r] + bvv);
      }
    }
  }
}

// ---------------------------------------------------------------- out-proj GEMM
__global__ __launch_bounds__(256, 4) void k_gemmo(
    const unsigned short* __restrict__ A, const unsigned short* __restrict__ Bt,
    const float* __restrict__ bias, unsigned short* __restrict__ out) {
  __shared__ unsigned short As[2][128 * 32];
  __shared__ unsigned short Bs[2][128 * 32];
  const int tid = threadIdx.x;
  const int lane = tid & 63, wave = tid >> 6;
  const int quad = lane >> 4, l16 = lane & 15;
  const int wm = wave >> 1, wn = wave & 1;
  const int id = blockIdx.x;  // 0..511
  const int xcd = id & 7, j = id >> 3;
  const int bx = (xcd << 3) | (j & 7), by = j >> 3;  // bx 0..63, by 0..7
  const int rb = bx * 128, cb = by * 128;

  floatx4 acc[4][4];
  const floatx4 vzero = {0.f, 0.f, 0.f, 0.f};
#pragma unroll
  for (int i = 0; i < 4; ++i)
#pragma unroll
    for (int jj = 0; jj < 4; ++jj) acc[i][jj] = vzero;

  GEMM_CORE(A, Bt, rb, cb);

#pragma unroll
  for (int ni = 0; ni < 4; ++ni) {
    const int col = cb + wn * 64 + ni * 16 + l16;
    const float bvv = bias[col];
#pragma unroll
    for (int mi = 0; mi < 4; ++mi) {
#pragma unroll
      for (int r = 0; r < 4; ++r) {
        const int row = rb + wm * 64 + mi * 16 + quad * 4 + r;
        out[(size_t)row * 1024 + col] = f2bf(acc[mi][ni][r] + bvv);
      }
    }
  }
}

// ---------------------------------------------------------------- flash attn v10
// = v8 (proven 79-82us: LDS-staged K/V, 1-barrier dbuf, cvt_pk, permlane
// transpose; r7's direct-L2 variant was 3.3x WORSE -- LDS is the broadcast
// amplifier, 4 waves share each tile) + ONE tweak: ALL 8 V ds_reads hoisted
// to the top of the kt iteration. In v8 they sat after the pack, exposing
// ~120cyc LDS latency to the first PV MFMA; hoisted, they complete under
// QK+exp+pack (~300cyc of non-LDS work). VGPR 52 -> ~90 (under the 128 cap
// at 4 blocks/CU).
__global__ __launch_bounds__(256, 4) void k_flash(
    const unsigned short* __restrict__ Q, const unsigned short* __restrict__ Kb,
    const unsigned short* __restrict__ Vt, unsigned short* __restrict__ AO) {
  __shared__ unsigned short Ks[2][64 * 64];
  __shared__ unsigned short Vs[2][64 * 64];
  const int tid = threadIdx.x, lane = tid & 63, wave = tid >> 6;
  const int quad = lane >> 4, l16 = lane & 15;
  const int g = blockIdx.x;            // 0..1023
  const int li = g >> 3;               // 0..127
  const int bh = (g & 7) * 8 + (li >> 4);
  const int qt = li & 15;              // 128-row q block
  const int b = bh >> 4, h = bh & 15;

  const unsigned short* Kh = Kb + (size_t)bh * 2048 * 64;
  const unsigned short* Vh = Vt + (size_t)bh * 64 * 2048;

  const float LAMBDA = 0.125f * 1.4426950408889634f;
  short8 aq[2][2];
  {
    const unsigned short* Qb = Q + ((size_t)bh * 2048 + qt * 128 + wave * 32) * 64;
#pragma unroll
    for (int qi = 0; qi < 2; ++qi)
#pragma unroll
      for (int c = 0; c < 2; ++c) {
        const short8 raw =
            *(const short8*)(Qb + (size_t)(qi * 16 + l16) * 64 + c * 32 + quad * 8);
        short8 sv;
#pragma unroll
        for (int j = 0; j < 8; ++j)
          sv[j] = (short)f2bf(bf2f((unsigned short)raw[j]) * LAMBDA);
        aq[qi][c] = sv;
      }
  }

  short8 onesv;  // bf16 1.0 in all 8 slots
#pragma unroll
  for (int j = 0; j < 8; ++j) onesv[j] = (short)0x3F80;

  const floatx4 vzero = {0.f, 0.f, 0.f, 0.f};
  floatx4 o[2][4];
#pragma unroll
  for (int qi = 0; qi < 2; ++qi)
#pragma unroll
    for (int di = 0; di < 4; ++di) o[qi][di] = vzero;
  floatx4 lacc[2] = {vzero, vzero};  // denominators, o-row layout (quad*4+r)

#define STAGE(ktile, buf)                                                      \
  {                                                                            \
    _Pragma("unroll") for (int r = 0; r < 2; ++r) {                            \
      const int c = r * 256 + tid;                                             \
      const int rw = c >> 3;                                                   \
      const int gc = ((c & 7) ^ (rw & 7)) * 8;                                 \
      GLD16(Kh + (size_t)((ktile) * 64 + rw) * 64 + gc,                        \
            &Ks[buf][(size_t)(r * 256 + wave * 64) * 8]);                      \
      GLD16(Vh + (size_t)rw * 2048 + (ktile) * 64 + gc,                        \
            &Vs[buf][(size_t)(r * 256 + wave * 64) * 8]);                      \
    }                                                                          \
  }

  STAGE(0, 0);

  for (int kt = 0; kt < 32; ++kt) {
    const int cur = kt & 1;
    __syncthreads();  // drains prev prefetch (had full compute phase to land)
    if (kt + 1 < 32) STAGE(kt + 1, cur ^ 1);  // in flight during this compute

    const unsigned short* Kc = &Ks[cur][0];
    const unsigned short* Vc = &Vs[cur][0];

    // ALL LDS reads up front: K frags then V frags; the V-read latency hides
    // under QK MFMA + exp + pack (no LDS ops in between).
    short8 fk[4][2];  // [ni][cc]
#pragma unroll
    for (int ni = 0; ni < 4; ++ni)
#pragma unroll
      for (int cc = 0; cc < 2; ++cc)
        fk[ni][cc] = *(const short8*)(&Kc[(ni * 16 + l16) * 64 +
                                          (((cc * 4 + quad) ^ (l16 & 7)) << 3)]);
    short8 fv[4][2];  // [di][ch]
#pragma unroll
    for (int di = 0; di < 4; ++di)
#pragma unroll
      for (int ch = 0; ch < 2; ++ch)
        fv[di][ch] = *(const short8*)(&Vc[(di * 16 + l16) * 64 +
                                          (((ch * 4 + quad) ^ (l16 & 7)) << 3)]);

#pragma unroll
    for (int ch = 0; ch < 2; ++ch) {  // 32-key half of the 64-key tile
      // QK^T: p[key=(ch*2+x)*16+quad*4+r][q=l16]
      floatx4 pA[2], pB[2];
      __builtin_amdgcn_s_setprio(1);
#pragma unroll
      for (int qi = 0; qi < 2; ++qi) {
        floatx4 ta = vzero, tb = vzero;
#pragma unroll
        for (int cc = 0; cc < 2; ++cc) {
          ta = __builtin_amdgcn_mfma_f32_16x16x32_bf16(fk[ch * 2 + 0][cc], aq[qi][cc], ta, 0, 0, 0);
          tb = __builtin_amdgcn_mfma_f32_16x16x32_bf16(fk[ch * 2 + 1][cc], aq[qi][cc], tb, 0, 0, 0);
        }
        pA[qi] = ta;
        pB[qi] = tb;
      }
      __builtin_amdgcn_s_setprio(0);
#pragma unroll
      for (int qi = 0; qi < 2; ++qi)
#pragma unroll
        for (int r = 0; r < 4; ++r) {
          pA[qi][r] = EXP2(pA[qi][r]);
          pB[qi][r] = EXP2(pB[qi][r]);
        }
      // in-register transpose to PV A-operand: P[q=l16][key=ch*32+quad*8+j]
      short8 apv[2];
#pragma unroll
      for (int qi = 0; qi < 2; ++qi) {
        const unsigned A0 = cvtpk(pA[qi][0], pA[qi][1]);
        const unsigned A1 = cvtpk(pA[qi][2], pA[qi][3]);
        const unsigned B0 = cvtpk(pB[qi][0], pB[qi][1]);
        const unsigned B1 = cvtpk(pB[qi][2], pB[qi][3]);
        unsigned P0, Q0, P1, Q1, T0, T1, T2, T3;
        pl32(A0, B0, P0, Q0);
        pl32(A1, B1, P1, Q1);
        pl16(P0, Q0, T0, T2);
        pl16(P1, Q1, T1, T3);
        union { uintx4 u; short8 s; } cv;
        cv.u[0] = T0; cv.u[1] = T1; cv.u[2] = T2; cv.u[3] = T3;
        apv[qi] = cv.s;
      }
      // denominator + PV
      __builtin_amdgcn_s_setprio(1);
#pragma unroll
      for (int qi = 0; qi < 2; ++qi)
        lacc[qi] = __builtin_amdgcn_mfma_f32_16x16x32_bf16(apv[qi], onesv, lacc[qi], 0, 0, 0);
#pragma unroll
      for (int di = 0; di < 4; ++di)
#pragma unroll
        for (int qi = 0; qi < 2; ++qi)
          o[qi][di] = __builtin_amdgcn_mfma_f32_16x16x32_bf16(apv[qi], fv[di][ch], o[qi][di], 0, 0, 0);
      __builtin_amdgcn_s_setprio(0);
    }
  }

#pragma unroll
  for (int qi = 0; qi < 2; ++qi) {
    float invl[4];
#pragma unroll
    for (int r = 0; r < 4; ++r) invl[r] = __builtin_amdgcn_rcpf(lacc[qi][r]);
#pragma unroll
    for (int di = 0; di < 4; ++di) {
#pragma unroll
      for (int r = 0; r < 4; ++r) {
        const int s = qt * 128 + wave * 32 + qi * 16 + quad * 4 + r;
        const int col = h * 64 + di * 16 + l16;
        AO[((size_t)b * 2048 + s) * 1024 + col] = f2bf(o[qi][di][r] * invl[r]);
      }
    }
  }
#undef STAGE
}

// ---------------------------------------------------------------- residual+LN
__global__ __launch_bounds__(256) void k_ln(
    const unsigned short* __restrict__ proj, const float* __restrict__ xpe,
    const float* __restrict__ gamma, const float* __restrict__ beta,
    float* __restrict__ out) {
  const int row = blockIdx.x, tid = threadIdx.x;
  const int lane = tid & 63, wave = tid >> 6;
  const float4 xv = ((const float4*)(xpe + (size_t)row * 1024))[tid];
  const ushort4 pv = ((const ushort4*)(proj + (size_t)row * 1024))[tid];
  const float h0 = xv.x + bf2f(pv.x);
  const float h1 = xv.y + bf2f(pv.y);
  const float h2 = xv.z + bf2f(pv.z);
  const float h3 = xv.w + bf2f(pv.w);
  float s = h0 + h1 + h2 + h3;
  float s2 = h0 * h0 + h1 * h1 + h2 * h2 + h3 * h3;
#pragma unroll
  for (int m = 1; m < 64; m <<= 1) {
    s += __shfl_xor(s, m);
    s2 += __shfl_xor(s2, m);
  }
  __shared__ float rs[4], rq[4];
  if (lane == 0) { rs[wave] = s; rq[wave] = s2; }
  __syncthreads();
  s = rs[0] + rs[1] + rs[2] + rs[3];
  s2 = rq[0] + rq[1] + rq[2] + rq[3];
  const float mu = s * (1.f / 1024.f);
  const float var = s2 * (1.f / 1024.f) - mu * mu;
  const float rstd = rsqrtf(var + 1e-5f);
  const float4 gv = ((const float4*)gamma)[tid];
  const float4 bvv = ((const float4*)beta)[tid];
  float4 ov;
  ov.x = (h0 - mu) * rstd * gv.x + bvv.x;
  ov.y = (h1 - mu) * rstd * gv.y + bvv.y;
  ov.z = (h2 - mu) * rstd * gv.z + bvv.z;
  ov.w = (h3 - mu) * rstd * gv.w + bvv.w;
  ((float4*)(out + (size_t)row * 1024))[tid] = ov;
}

// ---------------------------------------------------------------- launch
extern "C" void kernel_launch(void* const* d_in, const int* in_sizes, int n_in,
                              void* d_out, int out_size, void* d_ws, size_t ws_size,
                              hipStream_t stream) {
  const float* x = (const float*)d_in[0];
  const float* wq = (const float*)d_in[1];
  const float* bq = (const float*)d_in[2];
  const float* wk = (const float*)d_in[3];
  const float* bk = (const float*)d_in[4];
  const float* wv = (const float*)d_in[5];
  const float* bv = (const float*)d_in[6];
  const float* wo = (const float*)d_in[7];
  const float* bo = (const float*)d_in[8];
  const float* gamma = (const float*)d_in[9];
  const float* beta = (const float*)d_in[10];
  const float* pe = (const float*)d_in[11];

  if (ws_size < 125829120) return;  // need 120 MB scratch

  char* w = (char*)d_ws;
  unsigned short* wt = (unsigned short*)(w);               // 4x 1024x1024 bf16 (8 MB)
  float* xpef = (float*)(w + 8388608);                     // 8192x1024 f32 (32 MB)
  unsigned short* xpeb = (unsigned short*)(w + 41943040);  // 8192x1024 bf16 (16 MB)
  unsigned short* qb = (unsigned short*)(w + 58720256);    // 16 MB
  unsigned short* kb = (unsigned short*)(w + 75497472);    // 16 MB
  unsigned short* vtb = (unsigned short*)(w + 92274688);   // 16 MB
  unsigned short* aob = (unsigned short*)(w + 109051904);  // 16 MB
  unsigned short* projb = qb;                              // alias: Q dead after flash

  k_prep<<<9216, 256, 0, stream>>>(x, pe, wq, wk, wv, wo, wt, xpef, xpeb);
  k_gemmqk<<<256, 512, 0, stream>>>(xpeb, wt, bq, bk, qb, kb);
  k_gemmvt<<<512, 256, 0, stream>>>(xpeb, wt, bv, vtb);
  k_flash<<<1024, 256, 0, stream>>>(qb, kb, vtb, aob);
  k_gemmo<<<512, 256, 0, stream>>>(aob, wt + 3145728, bo, projb);
  k_ln<<<8192, 256, 0, stream>>>(projb, xpef, gamma, beta, (float*)d_out);
}

// Round 9
// 309.486 us; speedup vs baseline: 1.6484x; 1.2096x over previous
//
#include <hip/hip_runtime.h>

#define DEV __device__ __forceinline__

typedef __attribute__((ext_vector_type(4))) float floatx4;
typedef __attribute__((ext_vector_type(8))) short short8;
typedef __attribute__((ext_vector_type(4))) unsigned uintx4;

DEV unsigned short f2bf(float f) {
  unsigned u = __float_as_uint(f);
  u += 0x7FFF + ((u >> 16) & 1);
  return (unsigned short)(u >> 16);
}
DEV float bf2f(unsigned short h) { return __uint_as_float(((unsigned)h) << 16); }

// pack two f32 -> bf16x2 dword: single VOP3
DEV unsigned cvtpk(float lo, float hi) {
  unsigned r;
  asm("v_cvt_pk_bf16_f32 %0, %1, %2" : "=v"(r) : "v"(lo), "v"(hi));
  return r;
}

#if __has_builtin(__builtin_amdgcn_exp2f)
#define EXP2(x) __builtin_amdgcn_exp2f(x)
#else
#define EXP2(x) exp2f(x)
#endif

#define GLD16(g, l)                                                            \
  __builtin_amdgcn_global_load_lds(                                            \
      (const __attribute__((address_space(1))) void*)(g),                      \
      (__attribute__((address_space(3))) void*)(l), 16, 0, 0)

DEV int laneid() {
  return __builtin_amdgcn_mbcnt_hi(~0u, __builtin_amdgcn_mbcnt_lo(~0u, 0));
}

// (r0, r1) = cross-lane swap: r0 = [a.lo32 | b.lo32], r1 = [a.hi32 | b.hi32]
DEV void pl32(unsigned a, unsigned b, unsigned& r0, unsigned& r1) {
#if __has_builtin(__builtin_amdgcn_permlane32_swap)
  auto r = __builtin_amdgcn_permlane32_swap(a, b, false, false);
  r0 = (unsigned)r[0];
  r1 = (unsigned)r[1];
#else
  const int ln = laneid();
  const int ix = (ln ^ 32) << 2;
  const unsigned xa = (unsigned)__builtin_amdgcn_ds_bpermute(ix, (int)a);
  const unsigned xb = (unsigned)__builtin_amdgcn_ds_bpermute(ix, (int)b);
  const bool hi = (ln & 32) != 0;
  r0 = hi ? xb : a;
  r1 = hi ? b : xa;
#endif
}

// (r0, r1) per 32-half: r0 = [a.q0 | b.q0 | a.q2 | b.q2], r1 = [a.q1 | b.q1 | a.q3 | b.q3]
DEV void pl16(unsigned a, unsigned b, unsigned& r0, unsigned& r1) {
#if __has_builtin(__builtin_amdgcn_permlane16_swap)
  auto r = __builtin_amdgcn_permlane16_swap(a, b, false, false);
  r0 = (unsigned)r[0];
  r1 = (unsigned)r[1];
#else
  const int ln = laneid();
  const int ix = (ln ^ 16) << 2;
  const unsigned xa = (unsigned)__builtin_amdgcn_ds_bpermute(ix, (int)a);
  const unsigned xb = (unsigned)__builtin_amdgcn_ds_bpermute(ix, (int)b);
  const bool q1 = (ln & 16) != 0;
  r0 = q1 ? xb : a;
  r1 = q1 ? b : xa;
#endif
}

// ---------------------------------------------------------------- prep
__global__ void k_prep(const float* __restrict__ x, const float* __restrict__ pe,
                       const float* __restrict__ w0, const float* __restrict__ w1,
                       const float* __restrict__ w2, const float* __restrict__ w3,
                       unsigned short* __restrict__ wt, float* __restrict__ xf,
                       unsigned short* __restrict__ xb) {
  __shared__ float t[64][65];
  const int bid = blockIdx.x, tid = threadIdx.x;
  if (bid < 1024) {
    const int z = bid >> 8, rem = bid & 255;
    const int bx = rem & 15, by = rem >> 4;
    const int tx = tid & 63, ty = tid >> 6;
    const float* wsel = (z == 0) ? w0 : (z == 1) ? w1 : (z == 2) ? w2 : w3;
    unsigned short* out = wt + (size_t)z * 1048576;
    const int k0 = bx * 64, n0 = by * 64;
    for (int i = ty; i < 64; i += 4)
      t[i][tx] = wsel[(size_t)(k0 + i) * 1024 + n0 + tx];
    __syncthreads();
    for (int i = ty; i < 64; i += 4)
      out[(size_t)(n0 + i) * 1024 + k0 + tx] = f2bf(t[tx][i]);
  } else {
    const int idx = (bid - 1024) * 256 + tid;  // float4 index, 2M total
    const int row = idx >> 8;
    const int c4 = idx & 255;
    const int s = row & 2047;
    const float4 xv = ((const float4*)x)[idx];
    const float4 pv = ((const float4*)pe)[s * 256 + c4];
    float4 r;
    r.x = xv.x + pv.x; r.y = xv.y + pv.y; r.z = xv.z + pv.z; r.w = xv.w + pv.w;
    ((float4*)xf)[idx] = r;
    ushort4 o;
    o.x = f2bf(r.x); o.y = f2bf(r.y); o.z = f2bf(r.z); o.w = f2bf(r.w);
    ((ushort4*)xb)[idx] = o;
  }
}

// ---------------------------------------------------------------- GEMM core
// 128x128 tile, BK=32 double-buffered, 1 barrier/step. 2-way-safe swizzle
// (chunk ^ ((row>>1)&3)), applied both sides (stage source + frag read).
#define GSTAGE(Aptr, Bptr, RB, CB, ks, buf)                                    \
  {                                                                            \
    _Pragma("unroll") for (int r = 0; r < 2; ++r) {                            \
      const int c = r * 256 + tid;                                             \
      const int rw = c >> 2;                                                   \
      const int gc = ((c & 3) ^ ((rw >> 1) & 3)) << 3;                         \
      GLD16((Aptr) + (size_t)((RB) + rw) * 1024 + (ks) * 32 + gc,              \
            As[buf] + (size_t)(r * 256 + wave * 64) * 8);                      \
      GLD16((Bptr) + (size_t)((CB) + rw) * 1024 + (ks) * 32 + gc,              \
            Bs[buf] + (size_t)(r * 256 + wave * 64) * 8);                      \
    }                                                                          \
  }

#define GEMM_CORE(Aptr, Bptr, RB, CB)                                          \
  GSTAGE(Aptr, Bptr, RB, CB, 0, 0);                                            \
  for (int ks = 0; ks < 32; ++ks) {                                            \
    const int cur = ks & 1;                                                    \
    __syncthreads();                                                           \
    if (ks + 1 < 32) GSTAGE(Aptr, Bptr, RB, CB, ks + 1, cur ^ 1);              \
    short8 fa[4], fb[4];                                                       \
    _Pragma("unroll") for (int i = 0; i < 4; ++i) {                            \
      fa[i] = *(const short8*)(As[cur] + (wm * 64 + i * 16 + l16) * 32 +       \
                               ((quad ^ ((l16 >> 1) & 3)) << 3));              \
      fb[i] = *(const short8*)(Bs[cur] + (wn * 64 + i * 16 + l16) * 32 +       \
                               ((quad ^ ((l16 >> 1) & 3)) << 3));              \
    }                                                                          \
    _Pragma("unroll") for (int mi = 0; mi < 4; ++mi)                           \
        _Pragma("unroll") for (int ni = 0; ni < 4; ++ni) acc[mi][ni] =         \
        __builtin_amdgcn_mfma_f32_16x16x32_bf16(fa[mi], fb[ni],                \
                                                acc[mi][ni], 0, 0, 0);         \
  }

// ---------------------------------------------------------------- QK GEMM (256^2)
// 256 blocks = exactly 1/CU, no tail, balanced.
__global__ __launch_bounds__(512, 2) void k_gemmqk(
    const unsigned short* __restrict__ xpeb, const unsigned short* __restrict__ wt,
    const float* __restrict__ bqp, const float* __restrict__ bkp,
    unsigned short* __restrict__ qb, unsigned short* __restrict__ kb) {
  __shared__ unsigned short As[2][256 * 32];
  __shared__ unsigned short Bs[2][256 * 32];
  const int tid = threadIdx.x;
  const int lane = tid & 63, wave = tid >> 6;   // wave 0..7
  const int quad = lane >> 4, l16 = lane & 15;
  const int wm = wave >> 2, wn = wave & 3;      // 2M x 4N wave grid
  const int id = blockIdx.x;                    // 0..255
  const int xcd = id & 7, j = id >> 3;          // j 0..31
  const int bx = (xcd << 2) | (j & 3);          // 0..31
  const int by = j >> 2;                        // 0..7
  const int rb = bx * 256, cb = by * 256;

  floatx4 acc[8][4];
  const floatx4 vzero = {0.f, 0.f, 0.f, 0.f};
#pragma unroll
  for (int i = 0; i < 8; ++i)
#pragma unroll
    for (int jj = 0; jj < 4; ++jj) acc[i][jj] = vzero;

#define QSTAGE(ks, buf)                                                        \
  {                                                                            \
    _Pragma("unroll") for (int r = 0; r < 2; ++r) {                            \
      const int c = r * 512 + tid;                                             \
      const int rw = c >> 2;                                                   \
      const int gc = ((c & 3) ^ ((rw >> 1) & 3)) << 3;                         \
      GLD16(xpeb + (size_t)(rb + rw) * 1024 + (ks) * 32 + gc,                  \
            As[buf] + (size_t)(r * 512 + wave * 64) * 8);                      \
      GLD16(wt + (size_t)(cb + rw) * 1024 + (ks) * 32 + gc,                    \
            Bs[buf] + (size_t)(r * 512 + wave * 64) * 8);                      \
    }                                                                          \
  }

  QSTAGE(0, 0);
  for (int ks = 0; ks < 32; ++ks) {
    const int cur = ks & 1;
    __syncthreads();
    if (ks + 1 < 32) QSTAGE(ks + 1, cur ^ 1);
    short8 fa[8], fb[4];
#pragma unroll
    for (int i = 0; i < 8; ++i)
      fa[i] = *(const short8*)(As[cur] + (wm * 128 + i * 16 + l16) * 32 +
                               ((quad ^ ((l16 >> 1) & 3)) << 3));
#pragma unroll
    for (int i = 0; i < 4; ++i)
      fb[i] = *(const short8*)(Bs[cur] + (wn * 64 + i * 16 + l16) * 32 +
                               ((quad ^ ((l16 >> 1) & 3)) << 3));
#pragma unroll
    for (int mi = 0; mi < 8; ++mi)
#pragma unroll
      for (int ni = 0; ni < 4; ++ni)
        acc[mi][ni] = __builtin_amdgcn_mfma_f32_16x16x32_bf16(fa[mi], fb[ni],
                                                              acc[mi][ni], 0, 0, 0);
  }
#undef QSTAGE

  const int which = cb >> 10;  // by 0..3 -> q, 4..7 -> k
  const float* bias = which ? bkp : bqp;
  unsigned short* out = which ? kb : qb;
#pragma unroll
  for (int ni = 0; ni < 4; ++ni) {
    const int col = cb + wn * 64 + ni * 16 + l16;
    const int cl = col & 1023;
    const float bvv = bias[cl];
    const int hh = cl >> 6, d = cl & 63;
#pragma unroll
    for (int mi = 0; mi < 8; ++mi) {
#pragma unroll
      for (int r = 0; r < 4; ++r) {
        const int row = rb + wm * 128 + mi * 16 + quad * 4 + r;
        const int bb = row >> 11, s = row & 2047;
        out[((size_t)(bb * 16 + hh) * 2048 + s) * 64 + d] = f2bf(acc[mi][ni][r] + bvv);
      }
    }
  }
}

// ---------------------------------------------------------------- Vt GEMM (128^2)
__global__ __launch_bounds__(256, 4) void k_gemmvt(
    const unsigned short* __restrict__ xpeb, const unsigned short* __restrict__ wt,
    const float* __restrict__ bvp, unsigned short* __restrict__ vtb) {
  __shared__ unsigned short As[2][128 * 32];
  __shared__ unsigned short Bs[2][128 * 32];
  const int tid = threadIdx.x;
  const int lane = tid & 63, wave = tid >> 6;
  const int quad = lane >> 4, l16 = lane & 15;
  const int wm = wave >> 1, wn = wave & 1;
  const int id = blockIdx.x;  // 0..511
  const int xcd = id & 7, j = id >> 3;
  const int by = (xcd << 3) | (j & 7), bx = j >> 3;  // by 0..63 token, bx 0..7 d_out
  const int rb = bx * 128, cb = by * 128;

  floatx4 acc[4][4];
  const floatx4 vzero = {0.f, 0.f, 0.f, 0.f};
#pragma unroll
  for (int i = 0; i < 4; ++i)
#pragma unroll
    for (int jj = 0; jj < 4; ++jj) acc[i][jj] = vzero;

  GEMM_CORE(wt + 2097152, xpeb, rb, cb);

#pragma unroll
  for (int mi = 0; mi < 4; ++mi) {
#pragma unroll
    for (int r = 0; r < 4; ++r) {
      const int row = rb + wm * 64 + mi * 16 + quad * 4 + r;  // d_out = h*64+d
      const float bvv = bvp[row];
#pragma unroll
      for (int ni = 0; ni < 4; ++ni) {
        const int col = cb + wn * 64 + ni * 16 + l16;  // token
        vtb[((size_t)(col >> 11) * 1024 + row) * 2048 + (col & 2047)] =
            f2bf(acc[mi][ni][r] + bvv);
      }
    }
  }
}

// ---------------------------------------------------------------- out-proj GEMM
__global__ __launch_bounds__(256, 4) void k_gemmo(
    const unsigned short* __restrict__ A, const unsigned short* __restrict__ Bt,
    const float* __restrict__ bias, unsigned short* __restrict__ out) {
  __shared__ unsigned short As[2][128 * 32];
  __shared__ unsigned short Bs[2][128 * 32];
  const int tid = threadIdx.x;
  const int lane = tid & 63, wave = tid >> 6;
  const int quad = lane >> 4, l16 = lane & 15;
  const int wm = wave >> 1, wn = wave & 1;
  const int id = blockIdx.x;  // 0..511
  const int xcd = id & 7, j = id >> 3;
  const int bx = (xcd << 3) | (j & 7), by = j >> 3;  // bx 0..63, by 0..7
  const int rb = bx * 128, cb = by * 128;

  floatx4 acc[4][4];
  const floatx4 vzero = {0.f, 0.f, 0.f, 0.f};
#pragma unroll
  for (int i = 0; i < 4; ++i)
#pragma unroll
    for (int jj = 0; jj < 4; ++jj) acc[i][jj] = vzero;

  GEMM_CORE(A, Bt, rb, cb);

#pragma unroll
  for (int ni = 0; ni < 4; ++ni) {
    const int col = cb + wn * 64 + ni * 16 + l16;
    const float bvv = bias[col];
#pragma unroll
    for (int mi = 0; mi < 4; ++mi) {
#pragma unroll
      for (int r = 0; r < 4; ++r) {
        const int row = rb + wm * 64 + mi * 16 + quad * 4 + r;
        out[(size_t)row * 1024 + col] = f2bf(acc[mi][ni][r] + bvv);
      }
    }
  }
}

// ---------------------------------------------------------------- flash attn v8 (exact revert)
// Round-8's V-hoist caused scratch spill (WRITE_SIZE 16MB -> 227MB, dur 149us):
// holding fk[4][2]+fv[4][2] live across the tile body exceeded the compiler's
// 64-VGPR allocation and it spilled instead of growing. This is the exact v8
// body (79.3/82.5us, VGPR 52, WRITE 16MB): short live ranges -- K frags read
// per-ch, V frags read per-di inside the PV loop.
__global__ __launch_bounds__(256, 4) void k_flash(
    const unsigned short* __restrict__ Q, const unsigned short* __restrict__ Kb,
    const unsigned short* __restrict__ Vt, unsigned short* __restrict__ AO) {
  __shared__ unsigned short Ks[2][64 * 64];
  __shared__ unsigned short Vs[2][64 * 64];
  const int tid = threadIdx.x, lane = tid & 63, wave = tid >> 6;
  const int quad = lane >> 4, l16 = lane & 15;
  const int g = blockIdx.x;            // 0..1023
  const int li = g >> 3;               // 0..127
  const int bh = (g & 7) * 8 + (li >> 4);
  const int qt = li & 15;              // 128-row q block
  const int b = bh >> 4, h = bh & 15;

  const unsigned short* Kh = Kb + (size_t)bh * 2048 * 64;
  const unsigned short* Vh = Vt + (size_t)bh * 64 * 2048;

  const float LAMBDA = 0.125f * 1.4426950408889634f;
  short8 aq[2][2];
  {
    const unsigned short* Qb = Q + ((size_t)bh * 2048 + qt * 128 + wave * 32) * 64;
#pragma unroll
    for (int qi = 0; qi < 2; ++qi)
#pragma unroll
      for (int c = 0; c < 2; ++c) {
        const short8 raw =
            *(const short8*)(Qb + (size_t)(qi * 16 + l16) * 64 + c * 32 + quad * 8);
        short8 sv;
#pragma unroll
        for (int j = 0; j < 8; ++j)
          sv[j] = (short)f2bf(bf2f((unsigned short)raw[j]) * LAMBDA);
        aq[qi][c] = sv;
      }
  }

  short8 onesv;  // bf16 1.0 in all 8 slots
#pragma unroll
  for (int j = 0; j < 8; ++j) onesv[j] = (short)0x3F80;

  const floatx4 vzero = {0.f, 0.f, 0.f, 0.f};
  floatx4 o[2][4];
#pragma unroll
  for (int qi = 0; qi < 2; ++qi)
#pragma unroll
    for (int di = 0; di < 4; ++di) o[qi][di] = vzero;
  floatx4 lacc[2] = {vzero, vzero};  // denominators, o-row layout (quad*4+r)

#define STAGE(ktile, buf)                                                      \
  {                                                                            \
    _Pragma("unroll") for (int r = 0; r < 2; ++r) {                            \
      const int c = r * 256 + tid;                                             \
      const int rw = c >> 3;                                                   \
      const int gc = ((c & 7) ^ (rw & 7)) * 8;                                 \
      GLD16(Kh + (size_t)((ktile) * 64 + rw) * 64 + gc,                        \
            &Ks[buf][(size_t)(r * 256 + wave * 64) * 8]);                      \
      GLD16(Vh + (size_t)rw * 2048 + (ktile) * 64 + gc,                        \
            &Vs[buf][(size_t)(r * 256 + wave * 64) * 8]);                      \
    }                                                                          \
  }

  STAGE(0, 0);

  for (int kt = 0; kt < 32; ++kt) {
    const int cur = kt & 1;
    __syncthreads();  // drains prev prefetch (had full compute phase to land)
    if (kt + 1 < 32) STAGE(kt + 1, cur ^ 1);  // in flight during this compute

    const unsigned short* Kc = &Ks[cur][0];
    const unsigned short* Vc = &Vs[cur][0];

#pragma unroll
    for (int ch = 0; ch < 2; ++ch) {  // 32-key half of the 64-key tile
      // K fragments for ni = 2ch (A) and 2ch+1 (B); cc = 32-wide d-slice
      short8 fkA[2], fkB[2];
#pragma unroll
      for (int cc = 0; cc < 2; ++cc) {
        const int sw = (((cc * 4 + quad) ^ (l16 & 7)) << 3);
        fkA[cc] = *(const short8*)(&Kc[((ch * 2 + 0) * 16 + l16) * 64 + sw]);
        fkB[cc] = *(const short8*)(&Kc[((ch * 2 + 1) * 16 + l16) * 64 + sw]);
      }
      // QK^T: p[key=ni*16+quad*4+r][q=l16]
      floatx4 pA[2], pB[2];
      __builtin_amdgcn_s_setprio(1);
#pragma unroll
      for (int qi = 0; qi < 2; ++qi) {
        floatx4 ta = vzero, tb = vzero;
#pragma unroll
        for (int cc = 0; cc < 2; ++cc) {
          ta = __builtin_amdgcn_mfma_f32_16x16x32_bf16(fkA[cc], aq[qi][cc], ta, 0, 0, 0);
          tb = __builtin_amdgcn_mfma_f32_16x16x32_bf16(fkB[cc], aq[qi][cc], tb, 0, 0, 0);
        }
        pA[qi] = ta;
        pB[qi] = tb;
      }
      __builtin_amdgcn_s_setprio(0);
#pragma unroll
      for (int qi = 0; qi < 2; ++qi)
#pragma unroll
        for (int r = 0; r < 4; ++r) {
          pA[qi][r] = EXP2(pA[qi][r]);
          pB[qi][r] = EXP2(pB[qi][r]);
        }
      // in-register transpose to PV A-operand: P[q=l16][key=ch*32+quad*8+j]
      short8 apv[2];
#pragma unroll
      for (int qi = 0; qi < 2; ++qi) {
        const unsigned A0 = cvtpk(pA[qi][0], pA[qi][1]);
        const unsigned A1 = cvtpk(pA[qi][2], pA[qi][3]);
        const unsigned B0 = cvtpk(pB[qi][0], pB[qi][1]);
        const unsigned B1 = cvtpk(pB[qi][2], pB[qi][3]);
        unsigned P0, Q0, P1, Q1, T0, T1, T2, T3;
        pl32(A0, B0, P0, Q0);
        pl32(A1, B1, P1, Q1);
        pl16(P0, Q0, T0, T2);
        pl16(P1, Q1, T1, T3);
        union { uintx4 u; short8 s; } cv;
        cv.u[0] = T0; cv.u[1] = T1; cv.u[2] = T2; cv.u[3] = T3;
        apv[qi] = cv.s;
      }
      // denominator + PV
      __builtin_amdgcn_s_setprio(1);
#pragma unroll
      for (int qi = 0; qi < 2; ++qi)
        lacc[qi] = __builtin_amdgcn_mfma_f32_16x16x32_bf16(apv[qi], onesv, lacc[qi], 0, 0, 0);
#pragma unroll
      for (int di = 0; di < 4; ++di) {
        const short8 fv = *(const short8*)(&Vc[(di * 16 + l16) * 64 +
                                               (((ch * 4 + quad) ^ (l16 & 7)) << 3)]);
#pragma unroll
        for (int qi = 0; qi < 2; ++qi)
          o[qi][di] = __builtin_amdgcn_mfma_f32_16x16x32_bf16(apv[qi], fv, o[qi][di], 0, 0, 0);
      }
      __builtin_amdgcn_s_setprio(0);
    }
  }

#pragma unroll
  for (int qi = 0; qi < 2; ++qi) {
    float invl[4];
#pragma unroll
    for (int r = 0; r < 4; ++r) invl[r] = __builtin_amdgcn_rcpf(lacc[qi][r]);
#pragma unroll
    for (int di = 0; di < 4; ++di) {
#pragma unroll
      for (int r = 0; r < 4; ++r) {
        const int s = qt * 128 + wave * 32 + qi * 16 + quad * 4 + r;
        const int col = h * 64 + di * 16 + l16;
        AO[((size_t)b * 2048 + s) * 1024 + col] = f2bf(o[qi][di][r] * invl[r]);
      }
    }
  }
#undef STAGE
}

// ---------------------------------------------------------------- residual+LN
__global__ __launch_bounds__(256) void k_ln(
    const unsigned short* __restrict__ proj, const float* __restrict__ xpe,
    const float* __restrict__ gamma, const float* __restrict__ beta,
    float* __restrict__ out) {
  const int row = blockIdx.x, tid = threadIdx.x;
  const int lane = tid & 63, wave = tid >> 6;
  const float4 xv = ((const float4*)(xpe + (size_t)row * 1024))[tid];
  const ushort4 pv = ((const ushort4*)(proj + (size_t)row * 1024))[tid];
  const float h0 = xv.x + bf2f(pv.x);
  const float h1 = xv.y + bf2f(pv.y);
  const float h2 = xv.z + bf2f(pv.z);
  const float h3 = xv.w + bf2f(pv.w);
  float s = h0 + h1 + h2 + h3;
  float s2 = h0 * h0 + h1 * h1 + h2 * h2 + h3 * h3;
#pragma unroll
  for (int m = 1; m < 64; m <<= 1) {
    s += __shfl_xor(s, m);
    s2 += __shfl_xor(s2, m);
  }
  __shared__ float rs[4], rq[4];
  if (lane == 0) { rs[wave] = s; rq[wave] = s2; }
  __syncthreads();
  s = rs[0] + rs[1] + rs[2] + rs[3];
  s2 = rq[0] + rq[1] + rq[2] + rq[3];
  const float mu = s * (1.f / 1024.f);
  const float var = s2 * (1.f / 1024.f) - mu * mu;
  const float rstd = rsqrtf(var + 1e-5f);
  const float4 gv = ((const float4*)gamma)[tid];
  const float4 bvv = ((const float4*)beta)[tid];
  float4 ov;
  ov.x = (h0 - mu) * rstd * gv.x + bvv.x;
  ov.y = (h1 - mu) * rstd * gv.y + bvv.y;
  ov.z = (h2 - mu) * rstd * gv.z + bvv.z;
  ov.w = (h3 - mu) * rstd * gv.w + bvv.w;
  ((float4*)(out + (size_t)row * 1024))[tid] = ov;
}

// ---------------------------------------------------------------- launch
extern "C" void kernel_launch(void* const* d_in, const int* in_sizes, int n_in,
                              void* d_out, int out_size, void* d_ws, size_t ws_size,
                              hipStream_t stream) {
  const float* x = (const float*)d_in[0];
  const float* wq = (const float*)d_in[1];
  const float* bq = (const float*)d_in[2];
  const float* wk = (const float*)d_in[3];
  const float* bk = (const float*)d_in[4];
  const float* wv = (const float*)d_in[5];
  const float* bv = (const float*)d_in[6];
  const float* wo = (const float*)d_in[7];
  const float* bo = (const float*)d_in[8];
  const float* gamma = (const float*)d_in[9];
  const float* beta = (const float*)d_in[10];
  const float* pe = (const float*)d_in[11];

  if (ws_size < 125829120) return;  // need 120 MB scratch

  char* w = (char*)d_ws;
  unsigned short* wt = (unsigned short*)(w);               // 4x 1024x1024 bf16 (8 MB)
  float* xpef = (float*)(w + 8388608);                     // 8192x1024 f32 (32 MB)
  unsigned short* xpeb = (unsigned short*)(w + 41943040);  // 8192x1024 bf16 (16 MB)
  unsigned short* qb = (unsigned short*)(w + 58720256);    // 16 MB
  unsigned short* kb = (unsigned short*)(w + 75497472);    // 16 MB
  unsigned short* vtb = (unsigned short*)(w + 92274688);   // 16 MB
  unsigned short* aob = (unsigned short*)(w + 109051904);  // 16 MB
  unsigned short* projb = qb;                              // alias: Q dead after flash

  k_prep<<<9216, 256, 0, stream>>>(x, pe, wq, wk, wv, wo, wt, xpef, xpeb);
  k_gemmqk<<<256, 512, 0, stream>>>(xpeb, wt, bq, bk, qb, kb);
  k_gemmvt<<<512, 256, 0, stream>>>(xpeb, wt, bv, vtb);
  k_flash<<<1024, 256, 0, stream>>>(qb, kb, vtb, aob);
  k_gemmo<<<512, 256, 0, stream>>>(aob, wt + 3145728, bo, projb);
  k_ln<<<8192, 256, 0, stream>>>(projb, xpef, gamma, beta, (float*)d_out);
}

// Round 10
// 285.624 us; speedup vs baseline: 1.7861x; 1.0835x over previous
//
#include <hip/hip_runtime.h>

#define DEV __device__ __forceinline__

typedef __attribute__((ext_vector_type(4))) float floatx4;
typedef __attribute__((ext_vector_type(8))) short short8;
typedef __attribute__((ext_vector_type(4))) unsigned uintx4;

DEV unsigned short f2bf(float f) {
  unsigned u = __float_as_uint(f);
  u += 0x7FFF + ((u >> 16) & 1);
  return (unsigned short)(u >> 16);
}
DEV float bf2f(unsigned short h) { return __uint_as_float(((unsigned)h) << 16); }

// pack two f32 -> bf16x2 dword: single VOP3
DEV unsigned cvtpk(float lo, float hi) {
  unsigned r;
  asm("v_cvt_pk_bf16_f32 %0, %1, %2" : "=v"(r) : "v"(lo), "v"(hi));
  return r;
}

#if __has_builtin(__builtin_amdgcn_exp2f)
#define EXP2(x) __builtin_amdgcn_exp2f(x)
#else
#define EXP2(x) exp2f(x)
#endif

#define GLD16(g, l)                                                            \
  __builtin_amdgcn_global_load_lds(                                            \
      (const __attribute__((address_space(1))) void*)(g),                      \
      (__attribute__((address_space(3))) void*)(l), 16, 0, 0)

DEV int laneid() {
  return __builtin_amdgcn_mbcnt_hi(~0u, __builtin_amdgcn_mbcnt_lo(~0u, 0));
}

// (r0, r1) = cross-lane swap: r0 = [a.lo32 | b.lo32], r1 = [a.hi32 | b.hi32]
DEV void pl32(unsigned a, unsigned b, unsigned& r0, unsigned& r1) {
#if __has_builtin(__builtin_amdgcn_permlane32_swap)
  auto r = __builtin_amdgcn_permlane32_swap(a, b, false, false);
  r0 = (unsigned)r[0];
  r1 = (unsigned)r[1];
#else
  const int ln = laneid();
  const int ix = (ln ^ 32) << 2;
  const unsigned xa = (unsigned)__builtin_amdgcn_ds_bpermute(ix, (int)a);
  const unsigned xb = (unsigned)__builtin_amdgcn_ds_bpermute(ix, (int)b);
  const bool hi = (ln & 32) != 0;
  r0 = hi ? xb : a;
  r1 = hi ? b : xa;
#endif
}

// (r0, r1) per 32-half: r0 = [a.q0 | b.q0 | a.q2 | b.q2], r1 = [a.q1 | b.q1 | a.q3 | b.q3]
DEV void pl16(unsigned a, unsigned b, unsigned& r0, unsigned& r1) {
#if __has_builtin(__builtin_amdgcn_permlane16_swap)
  auto r = __builtin_amdgcn_permlane16_swap(a, b, false, false);
  r0 = (unsigned)r[0];
  r1 = (unsigned)r[1];
#else
  const int ln = laneid();
  const int ix = (ln ^ 16) << 2;
  const unsigned xa = (unsigned)__builtin_amdgcn_ds_bpermute(ix, (int)a);
  const unsigned xb = (unsigned)__builtin_amdgcn_ds_bpermute(ix, (int)b);
  const bool q1 = (ln & 16) != 0;
  r0 = q1 ? xb : a;
  r1 = q1 ? b : xa;
#endif
}

// ---------------------------------------------------------------- prep
// blocks 0..1023: weight transpose+cast (W[K,N] f32 -> Wt[N,K] bf16)
// blocks 1024..9215: x+pe (f32 out for LN residual, bf16 out for GEMM A)
__global__ void k_prep(const float* __restrict__ x, const float* __restrict__ pe,
                       const float* __restrict__ w0, const float* __restrict__ w1,
                       const float* __restrict__ w2, const float* __restrict__ w3,
                       unsigned short* __restrict__ wt, float* __restrict__ xf,
                       unsigned short* __restrict__ xb) {
  __shared__ float t[64][65];
  const int bid = blockIdx.x, tid = threadIdx.x;
  if (bid < 1024) {
    const int z = bid >> 8, rem = bid & 255;
    const int bx = rem & 15, by = rem >> 4;
    const int tx = tid & 63, ty = tid >> 6;
    const float* wsel = (z == 0) ? w0 : (z == 1) ? w1 : (z == 2) ? w2 : w3;
    unsigned short* out = wt + (size_t)z * 1048576;
    const int k0 = bx * 64, n0 = by * 64;
    for (int i = ty; i < 64; i += 4)
      t[i][tx] = wsel[(size_t)(k0 + i) * 1024 + n0 + tx];
    __syncthreads();
    for (int i = ty; i < 64; i += 4)
      out[(size_t)(n0 + i) * 1024 + k0 + tx] = f2bf(t[tx][i]);
  } else {
    const int idx = (bid - 1024) * 256 + tid;  // float4 index, 2M total
    const int row = idx >> 8;
    const int c4 = idx & 255;
    const int s = row & 2047;
    const float4 xv = ((const float4*)x)[idx];
    const float4 pv = ((const float4*)pe)[s * 256 + c4];
    float4 r;
    r.x = xv.x + pv.x; r.y = xv.y + pv.y; r.z = xv.z + pv.z; r.w = xv.w + pv.w;
    ((float4*)xf)[idx] = r;
    ushort4 o;
    o.x = f2bf(r.x); o.y = f2bf(r.y); o.z = f2bf(r.z); o.w = f2bf(r.w);
    ((ushort4*)xb)[idx] = o;
  }
}

// ---------------------------------------------------------------- GEMM core (r0 original)
// BK=64 K-loop, XOR-swizzled LDS (rows 128B; chunk' = chunk ^ (row&7) keeps
// every ds_read_b128 <=2-way). 2 barriers per 64-K, 32 MFMA per barrier
// period. Evidence (r0-r9 decomposition): this BK=64 structure's non-flash
// pipeline time = 194-216us vs 223-228us for the BK=32/256^2 rewrites --
// 32 MFMA per barrier interval beats finer-grained staging here.
#define GEMM_CORE(Aptr, Bptr, RB, CB)                                          \
  for (int k0 = 0; k0 < 1024; k0 += 64) {                                      \
    _Pragma("unroll") for (int r = 0; r < 4; ++r) {                            \
      const int c = r * 256 + tid;                                             \
      const int rw = c >> 3;                                                   \
      const int gc = ((c & 7) ^ (rw & 7)) << 3;                                \
      GLD16((Aptr) + (size_t)((RB) + rw) * 1024 + k0 + gc,                     \
            As + (size_t)(r * 256 + wave * 64) * 8);                           \
      GLD16((Bptr) + (size_t)((CB) + rw) * 1024 + k0 + gc,                     \
            Bs + (size_t)(r * 256 + wave * 64) * 8);                           \
    }                                                                          \
    __syncthreads();                                                           \
    _Pragma("unroll") for (int kk = 0; kk < 2; ++kk) {                         \
      short8 fa[4], fb[4];                                                     \
      _Pragma("unroll") for (int i = 0; i < 4; ++i) {                          \
        fa[i] = *(const short8*)(As + (wm * 64 + i * 16 + l16) * 64 +          \
                                 (((kk * 4 + quad) ^ (l16 & 7)) << 3));        \
        fb[i] = *(const short8*)(Bs + (wn * 64 + i * 16 + l16) * 64 +          \
                                 (((kk * 4 + quad) ^ (l16 & 7)) << 3));        \
      }                                                                        \
      _Pragma("unroll") for (int mi = 0; mi < 4; ++mi)                         \
          _Pragma("unroll") for (int ni = 0; ni < 4; ++ni) acc[mi][ni] =       \
          __builtin_amdgcn_mfma_f32_16x16x32_bf16(fa[mi], fb[ni],              \
                                                  acc[mi][ni], 0, 0, 0);       \
    }                                                                          \
    __syncthreads();                                                           \
  }

// ---------------------------------------------------------------- QKV GEMMs (r0 original)
// blocks 0..1023: C[8192,2048] = xpeb . (wq|wk)^T -> q,k as [b,h,s,d]
//   XCD-banded: xcd = id&7 owns A-rows [xcd*1024, +1024) (2MB, L2-resident)
// blocks 1024..1535: Vt[1024,8192] = wt_v . xpeb^T -> [b,h,d,s]
__global__ __launch_bounds__(256, 4) void k_gemmqkvt(
    const unsigned short* __restrict__ xpeb, const unsigned short* __restrict__ wt,
    const float* __restrict__ bqp, const float* __restrict__ bkp,
    const float* __restrict__ bvp, unsigned short* __restrict__ qb,
    unsigned short* __restrict__ kb, unsigned short* __restrict__ vtb) {
  __shared__ unsigned short As[128 * 64];
  __shared__ unsigned short Bs[128 * 64];
  const int tid = threadIdx.x;
  const int lane = tid & 63, wave = tid >> 6;
  const int quad = lane >> 4, l16 = lane & 15;
  const int wm = wave >> 1, wn = wave & 1;
  const int id = blockIdx.x;

  floatx4 acc[4][4];
  const floatx4 vzero = {0.f, 0.f, 0.f, 0.f};
#pragma unroll
  for (int i = 0; i < 4; ++i)
#pragma unroll
    for (int j = 0; j < 4; ++j) acc[i][j] = vzero;

  if (id < 1024) {
    const int xcd = id & 7, j = id >> 3;
    const int bx = (xcd << 3) | (j & 7), by = j >> 3;  // bx 0..63, by 0..15
    const int rb = bx * 128, cb = by * 128;
    GEMM_CORE(xpeb, wt, rb, cb);
    const int which = cb >> 10;  // 0=q 1=k
    const float* bias = (which == 0) ? bqp : bkp;
    unsigned short* out = (which == 0) ? qb : kb;
#pragma unroll
    for (int ni = 0; ni < 4; ++ni) {
      const int col = cb + wn * 64 + ni * 16 + l16;
      const int cl = col & 1023;
      const float bvv = bias[cl];
      const int h = cl >> 6, d = cl & 63;
#pragma unroll
      for (int mi = 0; mi < 4; ++mi) {
#pragma unroll
        for (int r = 0; r < 4; ++r) {
          const int row = rb + wm * 64 + mi * 16 + quad * 4 + r;
          const int b = row >> 11, s = row & 2047;
          out[((size_t)(b * 16 + h) * 2048 + s) * 64 + d] = f2bf(acc[mi][ni][r] + bvv);
        }
      }
    }
  } else {
    const int id2 = id - 1024;  // 0..511
    const int xcd = id2 & 7, j = id2 >> 3;
    const int by = (xcd << 3) | (j & 7), bx = j >> 3;  // by 0..63 token, bx 0..7 d_out
    const int rb = bx * 128, cb = by * 128;
    GEMM_CORE(wt + 2097152, xpeb, rb, cb);
#pragma unroll
    for (int mi = 0; mi < 4; ++mi) {
#pragma unroll
      for (int r = 0; r < 4; ++r) {
        const int row = rb + wm * 64 + mi * 16 + quad * 4 + r;  // d_out = h*64+d
        const float bvv = bvp[row];
#pragma unroll
        for (int ni = 0; ni < 4; ++ni) {
          const int col = cb + wn * 64 + ni * 16 + l16;  // token
          vtb[((size_t)(col >> 11) * 1024 + row) * 2048 + (col & 2047)] =
              f2bf(acc[mi][ni][r] + bvv);
        }
      }
    }
  }
}

// ---------------------------------------------------------------- out-proj GEMM (r0 original)
__global__ __launch_bounds__(256, 4) void k_gemmo(
    const unsigned short* __restrict__ A, const unsigned short* __restrict__ Bt,
    const float* __restrict__ bias, unsigned short* __restrict__ out) {
  __shared__ unsigned short As[128 * 64];
  __shared__ unsigned short Bs[128 * 64];
  const int tid = threadIdx.x;
  const int lane = tid & 63, wave = tid >> 6;
  const int quad = lane >> 4, l16 = lane & 15;
  const int wm = wave >> 1, wn = wave & 1;
  const int id = blockIdx.x;  // 0..511
  const int xcd = id & 7, j = id >> 3;
  const int bx = (xcd << 3) | (j & 7), by = j >> 3;  // bx 0..63, by 0..7
  const int rb = bx * 128, cb = by * 128;

  floatx4 acc[4][4];
  const floatx4 vzero = {0.f, 0.f, 0.f, 0.f};
#pragma unroll
  for (int i = 0; i < 4; ++i)
#pragma unroll
    for (int jj = 0; jj < 4; ++jj) acc[i][jj] = vzero;

  GEMM_CORE(A, Bt, rb, cb);

#pragma unroll
  for (int ni = 0; ni < 4; ++ni) {
    const int col = cb + wn * 64 + ni * 16 + l16;
    const float bvv = bias[col];
#pragma unroll
    for (int mi = 0; mi < 4; ++mi) {
#pragma unroll
      for (int r = 0; r < 4; ++r) {
        const int row = rb + wm * 64 + mi * 16 + quad * 4 + r;
        out[(size_t)row * 1024 + col] = f2bf(acc[mi][ni][r] + bvv);
      }
    }
  }
}

// ---------------------------------------------------------------- flash attn v8 (proven 79-83us x3)
__global__ __launch_bounds__(256, 4) void k_flash(
    const unsigned short* __restrict__ Q, const unsigned short* __restrict__ Kb,
    const unsigned short* __restrict__ Vt, unsigned short* __restrict__ AO) {
  __shared__ unsigned short Ks[2][64 * 64];
  __shared__ unsigned short Vs[2][64 * 64];
  const int tid = threadIdx.x, lane = tid & 63, wave = tid >> 6;
  const int quad = lane >> 4, l16 = lane & 15;
  const int g = blockIdx.x;            // 0..1023
  const int li = g >> 3;               // 0..127
  const int bh = (g & 7) * 8 + (li >> 4);
  const int qt = li & 15;              // 128-row q block
  const int b = bh >> 4, h = bh & 15;

  const unsigned short* Kh = Kb + (size_t)bh * 2048 * 64;
  const unsigned short* Vh = Vt + (size_t)bh * 64 * 2048;

  const float LAMBDA = 0.125f * 1.4426950408889634f;
  short8 aq[2][2];
  {
    const unsigned short* Qb = Q + ((size_t)bh * 2048 + qt * 128 + wave * 32) * 64;
#pragma unroll
    for (int qi = 0; qi < 2; ++qi)
#pragma unroll
      for (int c = 0; c < 2; ++c) {
        const short8 raw =
            *(const short8*)(Qb + (size_t)(qi * 16 + l16) * 64 + c * 32 + quad * 8);
        short8 sv;
#pragma unroll
        for (int j = 0; j < 8; ++j)
          sv[j] = (short)f2bf(bf2f((unsigned short)raw[j]) * LAMBDA);
        aq[qi][c] = sv;
      }
  }

  short8 onesv;  // bf16 1.0 in all 8 slots
#pragma unroll
  for (int j = 0; j < 8; ++j) onesv[j] = (short)0x3F80;

  const floatx4 vzero = {0.f, 0.f, 0.f, 0.f};
  floatx4 o[2][4];
#pragma unroll
  for (int qi = 0; qi < 2; ++qi)
#pragma unroll
    for (int di = 0; di < 4; ++di) o[qi][di] = vzero;
  floatx4 lacc[2] = {vzero, vzero};  // denominators, o-row layout (quad*4+r)

#define STAGE(ktile, buf)                                                      \
  {                                                                            \
    _Pragma("unroll") for (int r = 0; r < 2; ++r) {                            \
      const int c = r * 256 + tid;                                             \
      const int rw = c >> 3;                                                   \
      const int gc = ((c & 7) ^ (rw & 7)) * 8;                                 \
      GLD16(Kh + (size_t)((ktile) * 64 + rw) * 64 + gc,                        \
            &Ks[buf][(size_t)(r * 256 + wave * 64) * 8]);                      \
      GLD16(Vh + (size_t)rw * 2048 + (ktile) * 64 + gc,                        \
            &Vs[buf][(size_t)(r * 256 + wave * 64) * 8]);                      \
    }                                                                          \
  }

  STAGE(0, 0);

  for (int kt = 0; kt < 32; ++kt) {
    const int cur = kt & 1;
    __syncthreads();  // drains prev prefetch (had full compute phase to land)
    if (kt + 1 < 32) STAGE(kt + 1, cur ^ 1);  // in flight during this compute

    const unsigned short* Kc = &Ks[cur][0];
    const unsigned short* Vc = &Vs[cur][0];

#pragma unroll
    for (int ch = 0; ch < 2; ++ch) {  // 32-key half of the 64-key tile
      // K fragments for ni = 2ch (A) and 2ch+1 (B); cc = 32-wide d-slice
      short8 fkA[2], fkB[2];
#pragma unroll
      for (int cc = 0; cc < 2; ++cc) {
        const int sw = (((cc * 4 + quad) ^ (l16 & 7)) << 3);
        fkA[cc] = *(const short8*)(&Kc[((ch * 2 + 0) * 16 + l16) * 64 + sw]);
        fkB[cc] = *(const short8*)(&Kc[((ch * 2 + 1) * 16 + l16) * 64 + sw]);
      }
      // QK^T: p[key=ni*16+quad*4+r][q=l16]
      floatx4 pA[2], pB[2];
      __builtin_amdgcn_s_setprio(1);
#pragma unroll
      for (int qi = 0; qi < 2; ++qi) {
        floatx4 ta = vzero, tb = vzero;
#pragma unroll
        for (int cc = 0; cc < 2; ++cc) {
          ta = __builtin_amdgcn_mfma_f32_16x16x32_bf16(fkA[cc], aq[qi][cc], ta, 0, 0, 0);
          tb = __builtin_amdgcn_mfma_f32_16x16x32_bf16(fkB[cc], aq[qi][cc], tb, 0, 0, 0);
        }
        pA[qi] = ta;
        pB[qi] = tb;
      }
      __builtin_amdgcn_s_setprio(0);
#pragma unroll
      for (int qi = 0; qi < 2; ++qi)
#pragma unroll
        for (int r = 0; r < 4; ++r) {
          pA[qi][r] = EXP2(pA[qi][r]);
          pB[qi][r] = EXP2(pB[qi][r]);
        }
      // in-register transpose to PV A-operand: P[q=l16][key=ch*32+quad*8+j]
      short8 apv[2];
#pragma unroll
      for (int qi = 0; qi < 2; ++qi) {
        const unsigned A0 = cvtpk(pA[qi][0], pA[qi][1]);
        const unsigned A1 = cvtpk(pA[qi][2], pA[qi][3]);
        const unsigned B0 = cvtpk(pB[qi][0], pB[qi][1]);
        const unsigned B1 = cvtpk(pB[qi][2], pB[qi][3]);
        unsigned P0, Q0, P1, Q1, T0, T1, T2, T3;
        pl32(A0, B0, P0, Q0);
        pl32(A1, B1, P1, Q1);
        pl16(P0, Q0, T0, T2);
        pl16(P1, Q1, T1, T3);
        union { uintx4 u; short8 s; } cv;
        cv.u[0] = T0; cv.u[1] = T1; cv.u[2] = T2; cv.u[3] = T3;
        apv[qi] = cv.s;
      }
      // denominator + PV
      __builtin_amdgcn_s_setprio(1);
#pragma unroll
      for (int qi = 0; qi < 2; ++qi)
        lacc[qi] = __builtin_amdgcn_mfma_f32_16x16x32_bf16(apv[qi], onesv, lacc[qi], 0, 0, 0);
#pragma unroll
      for (int di = 0; di < 4; ++di) {
        const short8 fv = *(const short8*)(&Vc[(di * 16 + l16) * 64 +
                                               (((ch * 4 + quad) ^ (l16 & 7)) << 3)]);
#pragma unroll
        for (int qi = 0; qi < 2; ++qi)
          o[qi][di] = __builtin_amdgcn_mfma_f32_16x16x32_bf16(apv[qi], fv, o[qi][di], 0, 0, 0);
      }
      __builtin_amdgcn_s_setprio(0);
    }
  }

#pragma unroll
  for (int qi = 0; qi < 2; ++qi) {
    float invl[4];
#pragma unroll
    for (int r = 0; r < 4; ++r) invl[r] = __builtin_amdgcn_rcpf(lacc[qi][r]);
#pragma unroll
    for (int di = 0; di < 4; ++di) {
#pragma unroll
      for (int r = 0; r < 4; ++r) {
        const int s = qt * 128 + wave * 32 + qi * 16 + quad * 4 + r;
        const int col = h * 64 + di * 16 + l16;
        AO[((size_t)b * 2048 + s) * 1024 + col] = f2bf(o[qi][di][r] * invl[r]);
      }
    }
  }
#undef STAGE
}

// ---------------------------------------------------------------- residual+LN
__global__ __launch_bounds__(256) void k_ln(
    const unsigned short* __restrict__ proj, const float* __restrict__ xpe,
    const float* __restrict__ gamma, const float* __restrict__ beta,
    float* __restrict__ out) {
  const int row = blockIdx.x, tid = threadIdx.x;
  const int lane = tid & 63, wave = tid >> 6;
  const float4 xv = ((const float4*)(xpe + (size_t)row * 1024))[tid];
  const ushort4 pv = ((const ushort4*)(proj + (size_t)row * 1024))[tid];
  const float h0 = xv.x + bf2f(pv.x);
  const float h1 = xv.y + bf2f(pv.y);
  const float h2 = xv.z + bf2f(pv.z);
  const float h3 = xv.w + bf2f(pv.w);
  float s = h0 + h1 + h2 + h3;
  float s2 = h0 * h0 + h1 * h1 + h2 * h2 + h3 * h3;
#pragma unroll
  for (int m = 1; m < 64; m <<= 1) {
    s += __shfl_xor(s, m);
    s2 += __shfl_xor(s2, m);
  }
  __shared__ float rs[4], rq[4];
  if (lane == 0) { rs[wave] = s; rq[wave] = s2; }
  __syncthreads();
  s = rs[0] + rs[1] + rs[2] + rs[3];
  s2 = rq[0] + rq[1] + rq[2] + rq[3];
  const float mu = s * (1.f / 1024.f);
  const float var = s2 * (1.f / 1024.f) - mu * mu;
  const float rstd = rsqrtf(var + 1e-5f);
  const float4 gv = ((const float4*)gamma)[tid];
  const float4 bvv = ((const float4*)beta)[tid];
  float4 ov;
  ov.x = (h0 - mu) * rstd * gv.x + bvv.x;
  ov.y = (h1 - mu) * rstd * gv.y + bvv.y;
  ov.z = (h2 - mu) * rstd * gv.z + bvv.z;
  ov.w = (h3 - mu) * rstd * gv.w + bvv.w;
  ((float4*)(out + (size_t)row * 1024))[tid] = ov;
}

// ---------------------------------------------------------------- launch
extern "C" void kernel_launch(void* const* d_in, const int* in_sizes, int n_in,
                              void* d_out, int out_size, void* d_ws, size_t ws_size,
                              hipStream_t stream) {
  const float* x = (const float*)d_in[0];
  const float* wq = (const float*)d_in[1];
  const float* bq = (const float*)d_in[2];
  const float* wk = (const float*)d_in[3];
  const float* bk = (const float*)d_in[4];
  const float* wv = (const float*)d_in[5];
  const float* bv = (const float*)d_in[6];
  const float* wo = (const float*)d_in[7];
  const float* bo = (const float*)d_in[8];
  const float* gamma = (const float*)d_in[9];
  const float* beta = (const float*)d_in[10];
  const float* pe = (const float*)d_in[11];

  if (ws_size < 125829120) return;  // need 120 MB scratch

  char* w = (char*)d_ws;
  unsigned short* wt = (unsigned short*)(w);               // 4x 1024x1024 bf16 (8 MB)
  float* xpef = (float*)(w + 8388608);                     // 8192x1024 f32 (32 MB)
  unsigned short* xpeb = (unsigned short*)(w + 41943040);  // 8192x1024 bf16 (16 MB)
  unsigned short* qb = (unsigned short*)(w + 58720256);    // 16 MB
  unsigned short* kb = (unsigned short*)(w + 75497472);    // 16 MB
  unsigned short* vtb = (unsigned short*)(w + 92274688);   // 16 MB
  unsigned short* aob = (unsigned short*)(w + 109051904);  // 16 MB
  unsigned short* projb = qb;                              // alias: Q dead after flash

  k_prep<<<9216, 256, 0, stream>>>(x, pe, wq, wk, wv, wo, wt, xpef, xpeb);
  k_gemmqkvt<<<1536, 256, 0, stream>>>(xpeb, wt, bq, bk, bv, qb, kb, vtb);
  k_flash<<<1024, 256, 0, stream>>>(qb, kb, vtb, aob);
  k_gemmo<<<512, 256, 0, stream>>>(aob, wt + 3145728, bo, projb);
  k_ln<<<8192, 256, 0, stream>>>(projb, xpef, gamma, beta, (float*)d_out);
}

// Round 11
// 272.481 us; speedup vs baseline: 1.8722x; 1.0482x over previous
//
#include <hip/hip_runtime.h>

#define DEV __device__ __forceinline__

typedef __attribute__((ext_vector_type(4))) float floatx4;
typedef __attribute__((ext_vector_type(8))) short short8;
typedef __attribute__((ext_vector_type(4))) unsigned uintx4;

DEV unsigned short f2bf(float f) {
  unsigned u = __float_as_uint(f);
  u += 0x7FFF + ((u >> 16) & 1);
  return (unsigned short)(u >> 16);
}
DEV float bf2f(unsigned short h) { return __uint_as_float(((unsigned)h) << 16); }

// pack two f32 -> bf16x2 dword: single VOP3
DEV unsigned cvtpk(float lo, float hi) {
  unsigned r;
  asm("v_cvt_pk_bf16_f32 %0, %1, %2" : "=v"(r) : "v"(lo), "v"(hi));
  return r;
}

#if __has_builtin(__builtin_amdgcn_exp2f)
#define EXP2(x) __builtin_amdgcn_exp2f(x)
#else
#define EXP2(x) exp2f(x)
#endif

#define GLD16(g, l)                                                            \
  __builtin_amdgcn_global_load_lds(                                            \
      (const __attribute__((address_space(1))) void*)(g),                      \
      (__attribute__((address_space(3))) void*)(l), 16, 0, 0)

DEV int laneid() {
  return __builtin_amdgcn_mbcnt_hi(~0u, __builtin_amdgcn_mbcnt_lo(~0u, 0));
}

// (r0, r1) = cross-lane swap: r0 = [a.lo32 | b.lo32], r1 = [a.hi32 | b.hi32]
DEV void pl32(unsigned a, unsigned b, unsigned& r0, unsigned& r1) {
#if __has_builtin(__builtin_amdgcn_permlane32_swap)
  auto r = __builtin_amdgcn_permlane32_swap(a, b, false, false);
  r0 = (unsigned)r[0];
  r1 = (unsigned)r[1];
#else
  const int ln = laneid();
  const int ix = (ln ^ 32) << 2;
  const unsigned xa = (unsigned)__builtin_amdgcn_ds_bpermute(ix, (int)a);
  const unsigned xb = (unsigned)__builtin_amdgcn_ds_bpermute(ix, (int)b);
  const bool hi = (ln & 32) != 0;
  r0 = hi ? xb : a;
  r1 = hi ? b : xa;
#endif
}

// (r0, r1) per 32-half: r0 = [a.q0 | b.q0 | a.q2 | b.q2], r1 = [a.q1 | b.q1 | a.q3 | b.q3]
DEV void pl16(unsigned a, unsigned b, unsigned& r0, unsigned& r1) {
#if __has_builtin(__builtin_amdgcn_permlane16_swap)
  auto r = __builtin_amdgcn_permlane16_swap(a, b, false, false);
  r0 = (unsigned)r[0];
  r1 = (unsigned)r[1];
#else
  const int ln = laneid();
  const int ix = (ln ^ 16) << 2;
  const unsigned xa = (unsigned)__builtin_amdgcn_ds_bpermute(ix, (int)a);
  const unsigned xb = (unsigned)__builtin_amdgcn_ds_bpermute(ix, (int)b);
  const bool q1 = (ln & 16) != 0;
  r0 = q1 ? xb : a;
  r1 = q1 ? b : xa;
#endif
}

// ---------------------------------------------------------------- prep
// blocks 0..1023: weight transpose+cast (W[K,N] f32 -> Wt[N,K] bf16)
// blocks 1024..9215: x+pe -> bf16 ONLY (r11: the f32 copy for LN was
// redundant -- LN now reads the bf16; saves 32MB of writes here + 16MB of
// reads in k_ln. Residual precision: +1 bf16 ulp (~0.008 abs) on h, ~0.006
// after LN; expected absmax 0.031 -> <=0.039.)
__global__ void k_prep(const float* __restrict__ x, const float* __restrict__ pe,
                       const float* __restrict__ w0, const float* __restrict__ w1,
                       const float* __restrict__ w2, const float* __restrict__ w3,
                       unsigned short* __restrict__ wt,
                       unsigned short* __restrict__ xb) {
  __shared__ float t[64][65];
  const int bid = blockIdx.x, tid = threadIdx.x;
  if (bid < 1024) {
    const int z = bid >> 8, rem = bid & 255;
    const int bx = rem & 15, by = rem >> 4;
    const int tx = tid & 63, ty = tid >> 6;
    const float* wsel = (z == 0) ? w0 : (z == 1) ? w1 : (z == 2) ? w2 : w3;
    unsigned short* out = wt + (size_t)z * 1048576;
    const int k0 = bx * 64, n0 = by * 64;
    for (int i = ty; i < 64; i += 4)
      t[i][tx] = wsel[(size_t)(k0 + i) * 1024 + n0 + tx];
    __syncthreads();
    for (int i = ty; i < 64; i += 4)
      out[(size_t)(n0 + i) * 1024 + k0 + tx] = f2bf(t[tx][i]);
  } else {
    const int idx = (bid - 1024) * 256 + tid;  // float4 index, 2M total
    const int row = idx >> 8;
    const int c4 = idx & 255;
    const int s = row & 2047;
    const float4 xv = ((const float4*)x)[idx];
    const float4 pv = ((const float4*)pe)[s * 256 + c4];
    ushort4 o;
    o.x = f2bf(xv.x + pv.x);
    o.y = f2bf(xv.y + pv.y);
    o.z = f2bf(xv.z + pv.z);
    o.w = f2bf(xv.w + pv.w);
    ((ushort4*)xb)[idx] = o;
  }
}

// ---------------------------------------------------------------- GEMM core (r0 original)
// BK=64 K-loop, XOR-swizzled LDS (rows 128B; chunk' = chunk ^ (row&7) keeps
// every ds_read_b128 <=2-way). 2 barriers per 64-K, 32 MFMA per barrier
// period. Evidence (r0-r10 decomposition): this BK=64 structure's non-flash
// pipeline = 194-216us vs 223-228us for the BK=32/256^2 rewrites.
#define GEMM_CORE(Aptr, Bptr, RB, CB)                                          \
  for (int k0 = 0; k0 < 1024; k0 += 64) {                                      \
    _Pragma("unroll") for (int r = 0; r < 4; ++r) {                            \
      const int c = r * 256 + tid;                                             \
      const int rw = c >> 3;                                                   \
      const int gc = ((c & 7) ^ (rw & 7)) << 3;                                \
      GLD16((Aptr) + (size_t)((RB) + rw) * 1024 + k0 + gc,                     \
            As + (size_t)(r * 256 + wave * 64) * 8);                           \
      GLD16((Bptr) + (size_t)((CB) + rw) * 1024 + k0 + gc,                     \
            Bs + (size_t)(r * 256 + wave * 64) * 8);                           \
    }                                                                          \
    __syncthreads();                                                           \
    _Pragma("unroll") for (int kk = 0; kk < 2; ++kk) {                         \
      short8 fa[4], fb[4];                                                     \
      _Pragma("unroll") for (int i = 0; i < 4; ++i) {                          \
        fa[i] = *(const short8*)(As + (wm * 64 + i * 16 + l16) * 64 +          \
                                 (((kk * 4 + quad) ^ (l16 & 7)) << 3));        \
        fb[i] = *(const short8*)(Bs + (wn * 64 + i * 16 + l16) * 64 +          \
                                 (((kk * 4 + quad) ^ (l16 & 7)) << 3));        \
      }                                                                        \
      _Pragma("unroll") for (int mi = 0; mi < 4; ++mi)                         \
          _Pragma("unroll") for (int ni = 0; ni < 4; ++ni) acc[mi][ni] =       \
          __builtin_amdgcn_mfma_f32_16x16x32_bf16(fa[mi], fb[ni],              \
                                                  acc[mi][ni], 0, 0, 0);       \
    }                                                                          \
    __syncthreads();                                                           \
  }

// ---------------------------------------------------------------- QKV GEMMs (r0 original)
__global__ __launch_bounds__(256, 4) void k_gemmqkvt(
    const unsigned short* __restrict__ xpeb, const unsigned short* __restrict__ wt,
    const float* __restrict__ bqp, const float* __restrict__ bkp,
    const float* __restrict__ bvp, unsigned short* __restrict__ qb,
    unsigned short* __restrict__ kb, unsigned short* __restrict__ vtb) {
  __shared__ unsigned short As[128 * 64];
  __shared__ unsigned short Bs[128 * 64];
  const int tid = threadIdx.x;
  const int lane = tid & 63, wave = tid >> 6;
  const int quad = lane >> 4, l16 = lane & 15;
  const int wm = wave >> 1, wn = wave & 1;
  const int id = blockIdx.x;

  floatx4 acc[4][4];
  const floatx4 vzero = {0.f, 0.f, 0.f, 0.f};
#pragma unroll
  for (int i = 0; i < 4; ++i)
#pragma unroll
    for (int j = 0; j < 4; ++j) acc[i][j] = vzero;

  if (id < 1024) {
    const int xcd = id & 7, j = id >> 3;
    const int bx = (xcd << 3) | (j & 7), by = j >> 3;  // bx 0..63, by 0..15
    const int rb = bx * 128, cb = by * 128;
    GEMM_CORE(xpeb, wt, rb, cb);
    const int which = cb >> 10;  // 0=q 1=k
    const float* bias = (which == 0) ? bqp : bkp;
    unsigned short* out = (which == 0) ? qb : kb;
#pragma unroll
    for (int ni = 0; ni < 4; ++ni) {
      const int col = cb + wn * 64 + ni * 16 + l16;
      const int cl = col & 1023;
      const float bvv = bias[cl];
      const int h = cl >> 6, d = cl & 63;
#pragma unroll
      for (int mi = 0; mi < 4; ++mi) {
#pragma unroll
        for (int r = 0; r < 4; ++r) {
          const int row = rb + wm * 64 + mi * 16 + quad * 4 + r;
          const int b = row >> 11, s = row & 2047;
          out[((size_t)(b * 16 + h) * 2048 + s) * 64 + d] = f2bf(acc[mi][ni][r] + bvv);
        }
      }
    }
  } else {
    const int id2 = id - 1024;  // 0..511
    const int xcd = id2 & 7, j = id2 >> 3;
    const int by = (xcd << 3) | (j & 7), bx = j >> 3;  // by 0..63 token, bx 0..7 d_out
    const int rb = bx * 128, cb = by * 128;
    GEMM_CORE(wt + 2097152, xpeb, rb, cb);
#pragma unroll
    for (int mi = 0; mi < 4; ++mi) {
#pragma unroll
      for (int r = 0; r < 4; ++r) {
        const int row = rb + wm * 64 + mi * 16 + quad * 4 + r;  // d_out = h*64+d
        const float bvv = bvp[row];
#pragma unroll
        for (int ni = 0; ni < 4; ++ni) {
          const int col = cb + wn * 64 + ni * 16 + l16;  // token
          vtb[((size_t)(col >> 11) * 1024 + row) * 2048 + (col & 2047)] =
              f2bf(acc[mi][ni][r] + bvv);
        }
      }
    }
  }
}

// ---------------------------------------------------------------- out-proj GEMM (r0 original)
__global__ __launch_bounds__(256, 4) void k_gemmo(
    const unsigned short* __restrict__ A, const unsigned short* __restrict__ Bt,
    const float* __restrict__ bias, unsigned short* __restrict__ out) {
  __shared__ unsigned short As[128 * 64];
  __shared__ unsigned short Bs[128 * 64];
  const int tid = threadIdx.x;
  const int lane = tid & 63, wave = tid >> 6;
  const int quad = lane >> 4, l16 = lane & 15;
  const int wm = wave >> 1, wn = wave & 1;
  const int id = blockIdx.x;  // 0..511
  const int xcd = id & 7, j = id >> 3;
  const int bx = (xcd << 3) | (j & 7), by = j >> 3;  // bx 0..63, by 0..7
  const int rb = bx * 128, cb = by * 128;

  floatx4 acc[4][4];
  const floatx4 vzero = {0.f, 0.f, 0.f, 0.f};
#pragma unroll
  for (int i = 0; i < 4; ++i)
#pragma unroll
    for (int jj = 0; jj < 4; ++jj) acc[i][jj] = vzero;

  GEMM_CORE(A, Bt, rb, cb);

#pragma unroll
  for (int ni = 0; ni < 4; ++ni) {
    const int col = cb + wn * 64 + ni * 16 + l16;
    const float bvv = bias[col];
#pragma unroll
    for (int mi = 0; mi < 4; ++mi) {
#pragma unroll
      for (int r = 0; r < 4; ++r) {
        const int row = rb + wm * 64 + mi * 16 + quad * 4 + r;
        out[(size_t)row * 1024 + col] = f2bf(acc[mi][ni][r] + bvv);
      }
    }
  }
}

// ---------------------------------------------------------------- flash attn v8 (proven 79-83us x4)
__global__ __launch_bounds__(256, 4) void k_flash(
    const unsigned short* __restrict__ Q, const unsigned short* __restrict__ Kb,
    const unsigned short* __restrict__ Vt, unsigned short* __restrict__ AO) {
  __shared__ unsigned short Ks[2][64 * 64];
  __shared__ unsigned short Vs[2][64 * 64];
  const int tid = threadIdx.x, lane = tid & 63, wave = tid >> 6;
  const int quad = lane >> 4, l16 = lane & 15;
  const int g = blockIdx.x;            // 0..1023
  const int li = g >> 3;               // 0..127
  const int bh = (g & 7) * 8 + (li >> 4);
  const int qt = li & 15;              // 128-row q block
  const int b = bh >> 4, h = bh & 15;

  const unsigned short* Kh = Kb + (size_t)bh * 2048 * 64;
  const unsigned short* Vh = Vt + (size_t)bh * 64 * 2048;

  const float LAMBDA = 0.125f * 1.4426950408889634f;
  short8 aq[2][2];
  {
    const unsigned short* Qb = Q + ((size_t)bh * 2048 + qt * 128 + wave * 32) * 64;
#pragma unroll
    for (int qi = 0; qi < 2; ++qi)
#pragma unroll
      for (int c = 0; c < 2; ++c) {
        const short8 raw =
            *(const short8*)(Qb + (size_t)(qi * 16 + l16) * 64 + c * 32 + quad * 8);
        short8 sv;
#pragma unroll
        for (int j = 0; j < 8; ++j)
          sv[j] = (short)f2bf(bf2f((unsigned short)raw[j]) * LAMBDA);
        aq[qi][c] = sv;
      }
  }

  short8 onesv;  // bf16 1.0 in all 8 slots
#pragma unroll
  for (int j = 0; j < 8; ++j) onesv[j] = (short)0x3F80;

  const floatx4 vzero = {0.f, 0.f, 0.f, 0.f};
  floatx4 o[2][4];
#pragma unroll
  for (int qi = 0; qi < 2; ++qi)
#pragma unroll
    for (int di = 0; di < 4; ++di) o[qi][di] = vzero;
  floatx4 lacc[2] = {vzero, vzero};  // denominators, o-row layout (quad*4+r)

#define STAGE(ktile, buf)                                                      \
  {                                                                            \
    _Pragma("unroll") for (int r = 0; r < 2; ++r) {                            \
      const int c = r * 256 + tid;                                             \
      const int rw = c >> 3;                                                   \
      const int gc = ((c & 7) ^ (rw & 7)) * 8;                                 \
      GLD16(Kh + (size_t)((ktile) * 64 + rw) * 64 + gc,                        \
            &Ks[buf][(size_t)(r * 256 + wave * 64) * 8]);                      \
      GLD16(Vh + (size_t)rw * 2048 + (ktile) * 64 + gc,                        \
            &Vs[buf][(size_t)(r * 256 + wave * 64) * 8]);                      \
    }                                                                          \
  }

  STAGE(0, 0);

  for (int kt = 0; kt < 32; ++kt) {
    const int cur = kt & 1;
    __syncthreads();  // drains prev prefetch (had full compute phase to land)
    if (kt + 1 < 32) STAGE(kt + 1, cur ^ 1);  // in flight during this compute

    const unsigned short* Kc = &Ks[cur][0];
    const unsigned short* Vc = &Vs[cur][0];

#pragma unroll
    for (int ch = 0; ch < 2; ++ch) {  // 32-key half of the 64-key tile
      // K fragments for ni = 2ch (A) and 2ch+1 (B); cc = 32-wide d-slice
      short8 fkA[2], fkB[2];
#pragma unroll
      for (int cc = 0; cc < 2; ++cc) {
        const int sw = (((cc * 4 + quad) ^ (l16 & 7)) << 3);
        fkA[cc] = *(const short8*)(&Kc[((ch * 2 + 0) * 16 + l16) * 64 + sw]);
        fkB[cc] = *(const short8*)(&Kc[((ch * 2 + 1) * 16 + l16) * 64 + sw]);
      }
      // QK^T: p[key=ni*16+quad*4+r][q=l16]
      floatx4 pA[2], pB[2];
      __builtin_amdgcn_s_setprio(1);
#pragma unroll
      for (int qi = 0; qi < 2; ++qi) {
        floatx4 ta = vzero, tb = vzero;
#pragma unroll
        for (int cc = 0; cc < 2; ++cc) {
          ta = __builtin_amdgcn_mfma_f32_16x16x32_bf16(fkA[cc], aq[qi][cc], ta, 0, 0, 0);
          tb = __builtin_amdgcn_mfma_f32_16x16x32_bf16(fkB[cc], aq[qi][cc], tb, 0, 0, 0);
        }
        pA[qi] = ta;
        pB[qi] = tb;
      }
      __builtin_amdgcn_s_setprio(0);
#pragma unroll
      for (int qi = 0; qi < 2; ++qi)
#pragma unroll
        for (int r = 0; r < 4; ++r) {
          pA[qi][r] = EXP2(pA[qi][r]);
          pB[qi][r] = EXP2(pB[qi][r]);
        }
      // in-register transpose to PV A-operand: P[q=l16][key=ch*32+quad*8+j]
      short8 apv[2];
#pragma unroll
      for (int qi = 0; qi < 2; ++qi) {
        const unsigned A0 = cvtpk(pA[qi][0], pA[qi][1]);
        const unsigned A1 = cvtpk(pA[qi][2], pA[qi][3]);
        const unsigned B0 = cvtpk(pB[qi][0], pB[qi][1]);
        const unsigned B1 = cvtpk(pB[qi][2], pB[qi][3]);
        unsigned P0, Q0, P1, Q1, T0, T1, T2, T3;
        pl32(A0, B0, P0, Q0);
        pl32(A1, B1, P1, Q1);
        pl16(P0, Q0, T0, T2);
        pl16(P1, Q1, T1, T3);
        union { uintx4 u; short8 s; } cv;
        cv.u[0] = T0; cv.u[1] = T1; cv.u[2] = T2; cv.u[3] = T3;
        apv[qi] = cv.s;
      }
      // denominator + PV
      __builtin_amdgcn_s_setprio(1);
#pragma unroll
      for (int qi = 0; qi < 2; ++qi)
        lacc[qi] = __builtin_amdgcn_mfma_f32_16x16x32_bf16(apv[qi], onesv, lacc[qi], 0, 0, 0);
#pragma unroll
      for (int di = 0; di < 4; ++di) {
        const short8 fv = *(const short8*)(&Vc[(di * 16 + l16) * 64 +
                                               (((ch * 4 + quad) ^ (l16 & 7)) << 3)]);
#pragma unroll
        for (int qi = 0; qi < 2; ++qi)
          o[qi][di] = __builtin_amdgcn_mfma_f32_16x16x32_bf16(apv[qi], fv, o[qi][di], 0, 0, 0);
      }
      __builtin_amdgcn_s_setprio(0);
    }
  }

#pragma unroll
  for (int qi = 0; qi < 2; ++qi) {
    float invl[4];
#pragma unroll
    for (int r = 0; r < 4; ++r) invl[r] = __builtin_amdgcn_rcpf(lacc[qi][r]);
#pragma unroll
    for (int di = 0; di < 4; ++di) {
#pragma unroll
      for (int r = 0; r < 4; ++r) {
        const int s = qt * 128 + wave * 32 + qi * 16 + quad * 4 + r;
        const int col = h * 64 + di * 16 + l16;
        AO[((size_t)b * 2048 + s) * 1024 + col] = f2bf(o[qi][di][r] * invl[r]);
      }
    }
  }
#undef STAGE
}

// ---------------------------------------------------------------- residual+LN
// r11: residual read from bf16 x+pe (16MB) instead of f32 copy (32MB).
__global__ __launch_bounds__(256) void k_ln(
    const unsigned short* __restrict__ proj, const unsigned short* __restrict__ xpeb,
    const float* __restrict__ gamma, const float* __restrict__ beta,
    float* __restrict__ out) {
  const int row = blockIdx.x, tid = threadIdx.x;
  const int lane = tid & 63, wave = tid >> 6;
  const ushort4 xv = ((const ushort4*)(xpeb + (size_t)row * 1024))[tid];
  const ushort4 pv = ((const ushort4*)(proj + (size_t)row * 1024))[tid];
  const float h0 = bf2f(xv.x) + bf2f(pv.x);
  const float h1 = bf2f(xv.y) + bf2f(pv.y);
  const float h2 = bf2f(xv.z) + bf2f(pv.z);
  const float h3 = bf2f(xv.w) + bf2f(pv.w);
  float s = h0 + h1 + h2 + h3;
  float s2 = h0 * h0 + h1 * h1 + h2 * h2 + h3 * h3;
#pragma unroll
  for (int m = 1; m < 64; m <<= 1) {
    s += __shfl_xor(s, m);
    s2 += __shfl_xor(s2, m);
  }
  __shared__ float rs[4], rq[4];
  if (lane == 0) { rs[wave] = s; rq[wave] = s2; }
  __syncthreads();
  s = rs[0] + rs[1] + rs[2] + rs[3];
  s2 = rq[0] + rq[1] + rq[2] + rq[3];
  const float mu = s * (1.f / 1024.f);
  const float var = s2 * (1.f / 1024.f) - mu * mu;
  const float rstd = rsqrtf(var + 1e-5f);
  const float4 gv = ((const float4*)gamma)[tid];
  const float4 bvv = ((const float4*)beta)[tid];
  float4 ov;
  ov.x = (h0 - mu) * rstd * gv.x + bvv.x;
  ov.y = (h1 - mu) * rstd * gv.y + bvv.y;
  ov.z = (h2 - mu) * rstd * gv.z + bvv.z;
  ov.w = (h3 - mu) * rstd * gv.w + bvv.w;
  ((float4*)(out + (size_t)row * 1024))[tid] = ov;
}

// ---------------------------------------------------------------- launch
extern "C" void kernel_launch(void* const* d_in, const int* in_sizes, int n_in,
                              void* d_out, int out_size, void* d_ws, size_t ws_size,
                              hipStream_t stream) {
  const float* x = (const float*)d_in[0];
  const float* wq = (const float*)d_in[1];
  const float* bq = (const float*)d_in[2];
  const float* wk = (const float*)d_in[3];
  const float* bk = (const float*)d_in[4];
  const float* wv = (const float*)d_in[5];
  const float* bv = (const float*)d_in[6];
  const float* wo = (const float*)d_in[7];
  const float* bo = (const float*)d_in[8];
  const float* gamma = (const float*)d_in[9];
  const float* beta = (const float*)d_in[10];
  const float* pe = (const float*)d_in[11];

  if (ws_size < 125829120) return;  // need 120 MB scratch

  char* w = (char*)d_ws;
  unsigned short* wt = (unsigned short*)(w);               // 4x 1024x1024 bf16 (8 MB)
  unsigned short* xpeb = (unsigned short*)(w + 41943040);  // 8192x1024 bf16 (16 MB)
  unsigned short* qb = (unsigned short*)(w + 58720256);    // 16 MB
  unsigned short* kb = (unsigned short*)(w + 75497472);    // 16 MB
  unsigned short* vtb = (unsigned short*)(w + 92274688);   // 16 MB
  unsigned short* aob = (unsigned short*)(w + 109051904);  // 16 MB
  unsigned short* projb = qb;                              // alias: Q dead after flash

  k_prep<<<9216, 256, 0, stream>>>(x, pe, wq, wk, wv, wo, wt, xpeb);
  k_gemmqkvt<<<1536, 256, 0, stream>>>(xpeb, wt, bq, bk, bv, qb, kb, vtb);
  k_flash<<<1024, 256, 0, stream>>>(qb, kb, vtb, aob);
  k_gemmo<<<512, 256, 0, stream>>>(aob, wt + 3145728, bo, projb);
  k_ln<<<8192, 256, 0, stream>>>(projb, xpeb, gamma, beta, (float*)d_out);
}